// Round 7
// baseline (479.776 us; speedup 1.0000x reference)
//
#include <hip/hip_runtime.h>
#include <hip/hip_bf16.h>

#define KL  2304   // 48*48
#define KC  64
#define KHS 48
#define KHH 96
#define OFFY (KHS*(KL + 1))    // flat offset for (p+48,q+48)

typedef __attribute__((ext_vector_type(8))) short bf16x8;
typedef __attribute__((ext_vector_type(4))) float f32x4;

static __device__ inline unsigned short f2bf(float x) {
    __hip_bfloat16 h = __float2bfloat16(x);
    return *reinterpret_cast<unsigned short*>(&h);
}
static __device__ inline float bf2f(unsigned short u) {
    unsigned v = ((unsigned)u) << 16;
    return __uint_as_float(v);
}

// ---------------- K0: downsample f,b; per-pixel |bd|^2; downsampled mask ----
__global__ __launch_bounds__(64) void k_prep(const float* __restrict__ f,
    const float* __restrict__ bsrc, const float* __restrict__ mask,
    float* __restrict__ fd, float* __restrict__ bd,
    float* __restrict__ nbuf, float* __restrict__ mdd)
{
    int blk = blockIdx.x;              // nb*KL blocks
    int p = blk % KL, bi = blk / KL;
    int y = p / KHS, x = p % KHS;
    int fy = 2*y + 1, fx = 2*x + 1;
    int c = threadIdx.x;
    size_t src = (((size_t)bi*KHH + fy)*KHH + fx)*KC + c;
    float fv = f[src], bv = bsrc[src];
    size_t dst = ((size_t)bi*KL + p)*KC + c;
    fd[dst] = fv;
    bd[dst] = bv;
    float s = bv*bv;
    #pragma unroll
    for (int off = 32; off > 0; off >>= 1) s += __shfl_down(s, off);
    if (c == 0) {
        nbuf[bi*KL + p] = s;
        mdd[bi*KL + p]  = mask[((size_t)bi*KHH + fy)*KHH + fx];
    }
}

// ------- K1: rnrm[q] = 1/max(sqrt(9-tap sum nb),1e-4); mm from mask --------
__global__ __launch_bounds__(256) void k_normmask(const float* __restrict__ nbuf,
    const float* __restrict__ mdd, float* __restrict__ rnrm, float* __restrict__ mm)
{
    int i = blockIdx.x*256 + threadIdx.x;   // nb*KL
    int q = i % KL, bi = i / KL;
    int v = q / KHS, u = q % KHS;
    float sn = 0.f, sm = 0.f;
    for (int dy = -1; dy <= 1; dy++) {
        int vv = v + dy; if ((unsigned)vv >= KHS) continue;
        for (int dx = -1; dx <= 1; dx++) {
            int uu = u + dx; if ((unsigned)uu >= KHS) continue;
            sn += nbuf[bi*KL + vv*KHS + uu];
            sm += mdd[bi*KL + vv*KHS + uu];
        }
    }
    rnrm[i] = 1.0f / fmaxf(sqrtf(sn), 1e-4f);
    mm[i]   = (sm == 0.0f) ? 1.0f : 0.0f;
}

// ------ K2': build split-bf16 x-shift-augmented operands, K=576 -------------
__global__ __launch_bounds__(64) void k_build_hilo(const float* __restrict__ fd,
    const float* __restrict__ bd, unsigned short* __restrict__ Ahat,
    unsigned short* __restrict__ Bhat)
{
    int blk = blockIdx.x;              // nb*KL
    int p = blk % KL, bi = blk / KL;
    int c = threadIdx.x;
    int px = p % KHS;
    unsigned short* Ap = Ahat + ((size_t)bi*KL + p)*576;
    unsigned short* Bp = Bhat + ((size_t)bi*KL + p)*576;
    #pragma unroll
    for (int dxi = 0; dxi < 3; dxi++) {
        int xx = px + dxi - 1;
        float av = 0.f, bv = 0.f;
        if ((unsigned)xx < KHS) {
            int pp = p + dxi - 1;
            av = fd[((size_t)bi*KL + pp)*KC + c];
            bv = bd[((size_t)bi*KL + pp)*KC + c];
        }
        unsigned short ah = f2bf(av);
        unsigned short al = f2bf(av - bf2f(ah));
        unsigned short bh = f2bf(bv);
        unsigned short bl = f2bf(bv - bf2f(bh));
        Ap[0*192 + dxi*64 + c] = ah;
        Ap[1*192 + dxi*64 + c] = ah;
        Ap[2*192 + dxi*64 + c] = al;
        Bp[0*192 + dxi*64 + c] = bh;
        Bp[1*192 + dxi*64 + c] = bl;
        Bp[2*192 + dxi*64 + c] = bh;
    }
}

// ------ MFMA GEMM: C = A * B^T with optional split-K ------------------------
// 128x128 tile, BK=32, KITERS k-steps per block. blockIdx.z = bi*nsplit + ks.
// global_load_lds width=16 staging; 64 B LDS rows, chunk-XOR swizzle.
template<int KITERS>
__global__ __launch_bounds__(256) void k_mfma_bt(const unsigned short* __restrict__ A,
    const unsigned short* __restrict__ B, float* __restrict__ C,
    int Ncols, size_t sA, size_t sB, size_t sC, int KDIM, int nsplit, size_t psize)
{
    int z = blockIdx.z;
    int ks = z % nsplit, bi = z / nsplit;
    int kbase = ks * KITERS * 32;
    int n0 = blockIdx.x*128, m0 = blockIdx.y*128;
    const unsigned short* Ab = A + (size_t)bi*sA;
    const unsigned short* Bb = B + (size_t)bi*sB;
    float* Cb = C + (size_t)ks*psize + (size_t)bi*sC;
    __shared__ unsigned short As[128*32];
    __shared__ unsigned short Bs[128*32];
    int t = threadIdx.x;
    int lane = t & 63, w = t >> 6;
    int l15 = lane & 15, quad = lane >> 4;
    int swf = (l15 >> 2) & 3;
    int wm = (w >> 1)*64, wn = (w & 1)*64;
    int srow = lane >> 2;
    int ch = lane & 3;
    f32x4 acc[4][4];
    #pragma unroll
    for (int i = 0; i < 4; i++)
        #pragma unroll
        for (int j = 0; j < 4; j++) acc[i][j] = (f32x4){0.f,0.f,0.f,0.f};

    for (int kk = 0; kk < KITERS; kk++) {
        int k0 = kbase + kk*32;
        #pragma unroll
        for (int i = 0; i < 2; i++) {
            int rbase = w*32 + i*16;
            int r = rbase + srow;
            int cs = (ch ^ ((r >> 2) & 3))*8;
            const unsigned short* ga = &Ab[(size_t)(m0 + r)*KDIM + k0 + cs];
            __builtin_amdgcn_global_load_lds(
                (const __attribute__((address_space(1))) void*)ga,
                (__attribute__((address_space(3))) void*)&As[rbase*32], 16, 0, 0);
            const unsigned short* gb = &Bb[(size_t)(n0 + r)*KDIM + k0 + cs];
            __builtin_amdgcn_global_load_lds(
                (const __attribute__((address_space(1))) void*)gb,
                (__attribute__((address_space(3))) void*)&Bs[rbase*32], 16, 0, 0);
        }
        __syncthreads();
        bf16x8 af[4], bfr[4];
        #pragma unroll
        for (int mi = 0; mi < 4; mi++)
            af[mi] = *(const bf16x8*)&As[(wm + mi*16 + l15)*32 + ((quad ^ swf)*8)];
        #pragma unroll
        for (int ni = 0; ni < 4; ni++)
            bfr[ni] = *(const bf16x8*)&Bs[(wn + ni*16 + l15)*32 + ((quad ^ swf)*8)];
        #pragma unroll
        for (int mi = 0; mi < 4; mi++)
            #pragma unroll
            for (int ni = 0; ni < 4; ni++)
                acc[mi][ni] = __builtin_amdgcn_mfma_f32_16x16x32_bf16(
                    af[mi], bfr[ni], acc[mi][ni], 0, 0, 0);
        __syncthreads();
    }
    #pragma unroll
    for (int mi = 0; mi < 4; mi++)
        #pragma unroll
        for (int ni = 0; ni < 4; ni++) {
            int col = n0 + wn + ni*16 + l15;
            #pragma unroll
            for (int r = 0; r < 4; r++) {
                int row = m0 + wm + mi*16 + quad*4 + r;
                Cb[(size_t)row*Ncols + col] = acc[mi][ni][r];
            }
        }
}

// ------ K3b: y-diagonal 3-tap * rnrm + fuse conv #1 -------------------------
__global__ __launch_bounds__(256) void k_fuse_a2(const float* __restrict__ T,
    const float* __restrict__ rnrm, const float* __restrict__ fw,
    float* __restrict__ Y1)
{
    __shared__ float Sl[10][260];
    int bi = blockIdx.z;
    int p0 = blockIdx.y*8, q0 = blockIdx.x*256;
    const float* Tb = T + (size_t)bi*KL*KL;
    const float* rn = rnrm + bi*KL;
    int t = threadIdx.x;
    for (int i = t; i < 10*258; i += 256) {
        int r = i / 258, c = i - r*258;
        int pp = p0 - 1 + r, qq = q0 - 1 + c;
        float s = 0.f;
        if ((unsigned)pp < KL && (unsigned)qq < KL) {
            size_t base = (size_t)pp*KL + qq;
            float acc = Tb[base];
            if (pp >= KHS && qq >= KHS)           acc += Tb[base - OFFY];
            if (pp < KL - KHS && qq < KL - KHS)   acc += Tb[base + OFFY];
            s = acc * rn[qq];
        }
        Sl[r][c] = s;
    }
    __syncthreads();
    float w[9];
    #pragma unroll
    for (int i = 0; i < 9; i++) w[i] = fw[i];
    int c = t, q = q0 + c;
    float h0[10], h1[10], h2[10];
    #pragma unroll
    for (int r = 0; r < 10; r++) {
        float s0 = Sl[r][c], s1 = Sl[r][c+1], s2 = Sl[r][c+2];
        h0[r] = w[0]*s0 + w[1]*s1 + w[2]*s2;
        h1[r] = w[3]*s0 + w[4]*s1 + w[5]*s2;
        h2[r] = w[6]*s0 + w[7]*s1 + w[8]*s2;
    }
    #pragma unroll
    for (int rr = 0; rr < 8; rr++) {
        Y1[((size_t)bi*KL + p0 + rr)*KL + q] = h0[rr] + h1[rr+1] + h2[rr+2];
    }
}

// ------ K5'' : fuse conv #2 (transposed flat) + softmax -> bf16 -------------
// One block per 4 consecutive tp; 6 shared input rows in LDS (1.5x reads).
// Wave w owns output row tp0+w; softmax is wave-local (36 elems/lane).
__global__ __launch_bounds__(256) void k_fuse_b(const float* __restrict__ Y1,
    const float* __restrict__ fw, const float* __restrict__ mm,
    unsigned short* __restrict__ Ybf)
{
    __shared__ float rowb[6][KL];   // 55296 B
    int blk = blockIdx.x;           // nb*576
    int tp0 = (blk % 576)*4;
    int bi  = blk / 576;
    int t = threadIdx.x;
    const float* Yb = Y1 + (size_t)bi*KL*KL;
    #pragma unroll
    for (int a = 0; a < 6; a++) {
        int t2 = tp0 - 1 + a;
        float4* dst = (float4*)&rowb[a][0];
        if ((unsigned)t2 < KL) {
            int pr = (t2 % KHS)*KHS + t2/KHS;
            const float4* src = (const float4*)&Yb[(size_t)pr*KL];
            for (int i = t; i < KL/4; i += 256) dst[i] = src[i];
        } else {
            float4 z = {0.f,0.f,0.f,0.f};
            for (int i = t; i < KL/4; i += 256) dst[i] = z;
        }
    }
    float w9[9];
    #pragma unroll
    for (int i = 0; i < 9; i++) w9[i] = fw[i];
    __syncthreads();
    int w = t >> 6, lane = t & 63;
    int tp = tp0 + w;
    int x = tp / KHS, y = tp - x*KHS;   // tp = x*48 + y
    int p = y*KHS + x;
    const float* mmb = mm + bi*KL;
    float vals[36];
    float lmax = -1e30f;
    for (int i = 0; i < 36; i++) {
        int q = lane + i*64;
        int v = q / KHS, u = q - v*KHS;
        int tq = u*KHS + v;
        float acc = 0.f;
        #pragma unroll
        for (int b = 0; b < 3; b++) {
            int s2 = tq + b - 1;
            if ((unsigned)s2 >= KL) continue;
            int qr = (s2 % KHS)*KHS + s2/KHS;
            acc += w9[b]*rowb[w][qr] + w9[3+b]*rowb[w+1][qr] + w9[6+b]*rowb[w+2][qr];
        }
        float val = acc * mmb[q] * 10.0f;
        vals[i] = val;
        lmax = fmaxf(lmax, val);
    }
    #pragma unroll
    for (int off = 32; off > 0; off >>= 1) lmax = fmaxf(lmax, __shfl_down(lmax, off));
    lmax = __shfl(lmax, 0);
    float lsum = 0.f;
    #pragma unroll
    for (int i = 0; i < 36; i++) {
        float e = __expf(vals[i] - lmax);
        vals[i] = e;
        lsum += e;
    }
    #pragma unroll
    for (int off = 32; off > 0; off >>= 1) lsum += __shfl_down(lsum, off);
    lsum = __shfl(lsum, 0);
    float inv = 1.0f / lsum;
    unsigned short* orow = Ybf + ((size_t)bi*KL + p)*KL;
    for (int i = 0; i < 36; i++) {
        int q = lane + i*64;
        orow[q] = f2bf(vals[i]*inv*mmb[q]);
    }
}

// ---------------- KR: Rt[n][k] bf16, n=(ky,kx,c), k=q -----------------------
__global__ __launch_bounds__(256) void k_buildRt(const float* __restrict__ bsrc,
    unsigned short* __restrict__ Rt)
{
    int idx = blockIdx.x*256 + threadIdx.x;   // nb*1024*288
    int k8 = idx % 288;
    int rest = idx / 288;
    int n  = rest % 1024;
    int bi = rest / 1024;
    int jj = n >> 6, c = n & 63;
    int ky = jj >> 2, kx = jj & 3;
    int k0 = k8*8;
    bf16x8 vv;
    #pragma unroll
    for (int j = 0; j < 8; j++) {
        int q = k0 + j;
        int v = q / KHS, u = q % KHS;
        int ry = 2*v + ky - 1, rx = 2*u + kx - 1;
        float val = 0.f;
        if ((unsigned)ry < KHH && (unsigned)rx < KHH)
            val = bsrc[(((size_t)bi*KHH + ry)*KHH + rx)*KC + c];
        vv[j] = (short)f2bf(val);
    }
    *(bf16x8*)&Rt[((size_t)bi*1024 + n)*KL + k0] = vv;
}

// -------- K8: overlap-add (adjoint of stride-2 4x4 SAME conv), sum split-K --
__global__ __launch_bounds__(256) void k_overlap(const float* __restrict__ P,
    float* __restrict__ out, size_t psize)
{
    size_t gid = (size_t)blockIdx.x*256 + threadIdx.x;   // nb*96*96*64
    int c = gid & 63;
    size_t r = gid >> 6;
    int ix = (int)(r % KHH); r /= KHH;
    int iy = (int)(r % KHH);
    int bi = (int)(r / KHH);
    const float* P1 = P + psize;
    float acc = 0.f;
    #pragma unroll
    for (int sy = 0; sy < 2; sy++) {
        int ky = (iy & 1) ? (sy*2) : (sy*2 + 1);
        int yp = (iy + 1 - ky) >> 1;
        if ((unsigned)yp >= KHS) continue;
        #pragma unroll
        for (int sx = 0; sx < 2; sx++) {
            int kx = (ix & 1) ? (sx*2) : (sx*2 + 1);
            int xp = (ix + 1 - kx) >> 1;
            if ((unsigned)xp >= KHS) continue;
            size_t idx = (((size_t)bi*KL + yp*KHS + xp)*16 + (ky*4 + kx))*64 + c;
            acc += P[idx] + P1[idx];
        }
    }
    out[gid] = 0.25f * acc;
}

extern "C" void kernel_launch(void* const* d_in, const int* in_sizes, int n_in,
                              void* d_out, int out_size, void* d_ws, size_t ws_size,
                              hipStream_t stream)
{
    const float* f    = (const float*)d_in[0];
    const float* b    = (const float*)d_in[1];
    const float* mask = (const float*)d_in[2];
    const float* fw   = (const float*)d_in[3];
    float* out = (float*)d_out;

    auto need = [](int nbc) -> size_t {
        return (size_t)nbc * (2ull*KL*KC + 4ull*KL + 2ull*(size_t)KL*KL) * 4ull;
    };
    int nbc = 4;
    if (need(nbc) > ws_size) nbc = 2;
    if (need(nbc) > ws_size) nbc = 1;

    for (int bi0 = 0; bi0 < 4; bi0 += nbc) {
        int nb = (4 - bi0 < nbc) ? (4 - bi0) : nbc;
        const float* fc = f    + (size_t)bi0*KHH*KHH*KC;
        const float* bc = b    + (size_t)bi0*KHH*KHH*KC;
        const float* mc = mask + (size_t)bi0*KHH*KHH;
        float* outc = out + (size_t)bi0*KHH*KHH*KC;

        float* w    = (float*)d_ws;
        float* fd   = w;  w += (size_t)nbc*KL*KC;
        float* bd   = w;  w += (size_t)nbc*KL*KC;
        float* nbuf = w;  w += (size_t)nbc*KL;
        float* mdd  = w;  w += (size_t)nbc*KL;
        float* rnrm = w;  w += (size_t)nbc*KL;
        float* mmb  = w;  w += (size_t)nbc*KL;
        float* bufA = w;  w += (size_t)nbc*KL*KL;
        float* bufB = w;
        // lifetimes:
        //  bufB: [Ahat|Bhat] (bf16) -> Y1 (fp32) -> [P0|P1] (fp32)
        //  bufA: T (fp32) -> [Ybf bf16 | Rt bf16]
        unsigned short* Ahat = (unsigned short*)bufB;
        unsigned short* Bhat = Ahat + (size_t)nbc*KL*576;
        float* Tbuf = bufA;
        float* Y1   = bufB;
        unsigned short* Ybf = (unsigned short*)bufA;
        unsigned short* Rtb = Ybf + (size_t)nbc*KL*KL;
        float* Pbuf = bufB;
        size_t psize = (size_t)nbc*KL*1024;   // one split-K partial

        k_prep      <<<nb*KL, 64, 0, stream>>>(fc, bc, mc, fd, bd, nbuf, mdd);
        k_normmask  <<<(nb*KL)/256, 256, 0, stream>>>(nbuf, mdd, rnrm, mmb);
        k_build_hilo<<<nb*KL, 64, 0, stream>>>(fd, bd, Ahat, Bhat);
        // T = Ahat * Bhat^T  (K=576, no split)
        k_mfma_bt<18><<<dim3(18, 18, nb), 256, 0, stream>>>(
            Ahat, Bhat, Tbuf, KL, (size_t)KL*576, (size_t)KL*576, (size_t)KL*KL,
            576, 1, 0);
        // y-diag 3-tap * rnrm + fuse1: T (bufA) -> Y1 (bufB)
        k_fuse_a2   <<<dim3(9, 288, nb), 256, 0, stream>>>(Tbuf, rnrm, fw, Y1);
        // fuse2 + softmax: Y1 (bufB) -> Ybf (bufA)
        k_fuse_b    <<<nb*576, 256, 0, stream>>>(Y1, fw, mmb, Ybf);
        k_buildRt   <<<(nb*1024*288)/256, 256, 0, stream>>>(bc, Rtb);
        // P = Ybf * Rt^T (K=2304, split-K=2 -> P0,P1)
        k_mfma_bt<36><<<dim3(8, 18, nb*2), 256, 0, stream>>>(
            Ybf, Rtb, Pbuf, 1024, (size_t)KL*KL, (size_t)1024*KL, (size_t)KL*1024,
            2304, 2, psize);
        k_overlap   <<<nb*KL, 256, 0, stream>>>(Pbuf, outc, psize);
    }
}

// Round 8
// 408.457 us; speedup vs baseline: 1.1746x; 1.1746x over previous
//
#include <hip/hip_runtime.h>
#include <hip/hip_bf16.h>

#define KL  2304   // 48*48
#define KC  64
#define KHS 48
#define KHH 96
#define OFFY (KHS*(KL + 1))    // flat offset for (p+48,q+48)

typedef __attribute__((ext_vector_type(8))) short bf16x8;
typedef __attribute__((ext_vector_type(4))) float f32x4;

static __device__ inline unsigned short f2bf(float x) {
    __hip_bfloat16 h = __float2bfloat16(x);
    return *reinterpret_cast<unsigned short*>(&h);
}
static __device__ inline float bf2f(unsigned short u) {
    unsigned v = ((unsigned)u) << 16;
    return __uint_as_float(v);
}

// ---------------- K0: downsample f,b; per-pixel |bd|^2; downsampled mask ----
__global__ __launch_bounds__(64) void k_prep(const float* __restrict__ f,
    const float* __restrict__ bsrc, const float* __restrict__ mask,
    float* __restrict__ fd, float* __restrict__ bd,
    float* __restrict__ nbuf, float* __restrict__ mdd)
{
    int blk = blockIdx.x;              // nb*KL blocks
    int p = blk % KL, bi = blk / KL;
    int y = p / KHS, x = p % KHS;
    int fy = 2*y + 1, fx = 2*x + 1;
    int c = threadIdx.x;
    size_t src = (((size_t)bi*KHH + fy)*KHH + fx)*KC + c;
    float fv = f[src], bv = bsrc[src];
    size_t dst = ((size_t)bi*KL + p)*KC + c;
    fd[dst] = fv;
    bd[dst] = bv;
    float s = bv*bv;
    #pragma unroll
    for (int off = 32; off > 0; off >>= 1) s += __shfl_down(s, off);
    if (c == 0) {
        nbuf[bi*KL + p] = s;
        mdd[bi*KL + p]  = mask[((size_t)bi*KHH + fy)*KHH + fx];
    }
}

// ------- K1: rnrm[q] = 1/max(sqrt(9-tap sum nb),1e-4); mm from mask --------
__global__ __launch_bounds__(256) void k_normmask(const float* __restrict__ nbuf,
    const float* __restrict__ mdd, float* __restrict__ rnrm, float* __restrict__ mm)
{
    int i = blockIdx.x*256 + threadIdx.x;   // nb*KL
    int q = i % KL, bi = i / KL;
    int v = q / KHS, u = q % KHS;
    float sn = 0.f, sm = 0.f;
    for (int dy = -1; dy <= 1; dy++) {
        int vv = v + dy; if ((unsigned)vv >= KHS) continue;
        for (int dx = -1; dx <= 1; dx++) {
            int uu = u + dx; if ((unsigned)uu >= KHS) continue;
            sn += nbuf[bi*KL + vv*KHS + uu];
            sm += mdd[bi*KL + vv*KHS + uu];
        }
    }
    rnrm[i] = 1.0f / fmaxf(sqrtf(sn), 1e-4f);
    mm[i]   = (sm == 0.0f) ? 1.0f : 0.0f;
}

// ------ K2': build split-bf16 x-shift-augmented operands, K=576 -------------
__global__ __launch_bounds__(64) void k_build_hilo(const float* __restrict__ fd,
    const float* __restrict__ bd, unsigned short* __restrict__ Ahat,
    unsigned short* __restrict__ Bhat)
{
    int blk = blockIdx.x;              // nb*KL
    int p = blk % KL, bi = blk / KL;
    int c = threadIdx.x;
    int px = p % KHS;
    unsigned short* Ap = Ahat + ((size_t)bi*KL + p)*576;
    unsigned short* Bp = Bhat + ((size_t)bi*KL + p)*576;
    #pragma unroll
    for (int dxi = 0; dxi < 3; dxi++) {
        int xx = px + dxi - 1;
        float av = 0.f, bv = 0.f;
        if ((unsigned)xx < KHS) {
            int pp = p + dxi - 1;
            av = fd[((size_t)bi*KL + pp)*KC + c];
            bv = bd[((size_t)bi*KL + pp)*KC + c];
        }
        unsigned short ah = f2bf(av);
        unsigned short al = f2bf(av - bf2f(ah));
        unsigned short bh = f2bf(bv);
        unsigned short bl = f2bf(bv - bf2f(bh));
        Ap[0*192 + dxi*64 + c] = ah;
        Ap[1*192 + dxi*64 + c] = ah;
        Ap[2*192 + dxi*64 + c] = al;
        Bp[0*192 + dxi*64 + c] = bh;
        Bp[1*192 + dxi*64 + c] = bl;
        Bp[2*192 + dxi*64 + c] = bh;
    }
}

// ------ MFMA GEMM: C = A * B^T with optional split-K ------------------------
template<int KITERS>
__global__ __launch_bounds__(256) void k_mfma_bt(const unsigned short* __restrict__ A,
    const unsigned short* __restrict__ B, float* __restrict__ C,
    int Ncols, size_t sA, size_t sB, size_t sC, int KDIM, int nsplit, size_t psize)
{
    int z = blockIdx.z;
    int ks = z % nsplit, bi = z / nsplit;
    int kbase = ks * KITERS * 32;
    int n0 = blockIdx.x*128, m0 = blockIdx.y*128;
    const unsigned short* Ab = A + (size_t)bi*sA;
    const unsigned short* Bb = B + (size_t)bi*sB;
    float* Cb = C + (size_t)ks*psize + (size_t)bi*sC;
    __shared__ unsigned short As[128*32];
    __shared__ unsigned short Bs[128*32];
    int t = threadIdx.x;
    int lane = t & 63, w = t >> 6;
    int l15 = lane & 15, quad = lane >> 4;
    int swf = (l15 >> 2) & 3;
    int wm = (w >> 1)*64, wn = (w & 1)*64;
    int srow = lane >> 2;
    int ch = lane & 3;
    f32x4 acc[4][4];
    #pragma unroll
    for (int i = 0; i < 4; i++)
        #pragma unroll
        for (int j = 0; j < 4; j++) acc[i][j] = (f32x4){0.f,0.f,0.f,0.f};

    for (int kk = 0; kk < KITERS; kk++) {
        int k0 = kbase + kk*32;
        #pragma unroll
        for (int i = 0; i < 2; i++) {
            int rbase = w*32 + i*16;
            int r = rbase + srow;
            int cs = (ch ^ ((r >> 2) & 3))*8;
            const unsigned short* ga = &Ab[(size_t)(m0 + r)*KDIM + k0 + cs];
            __builtin_amdgcn_global_load_lds(
                (const __attribute__((address_space(1))) void*)ga,
                (__attribute__((address_space(3))) void*)&As[rbase*32], 16, 0, 0);
            const unsigned short* gb = &Bb[(size_t)(n0 + r)*KDIM + k0 + cs];
            __builtin_amdgcn_global_load_lds(
                (const __attribute__((address_space(1))) void*)gb,
                (__attribute__((address_space(3))) void*)&Bs[rbase*32], 16, 0, 0);
        }
        __syncthreads();
        bf16x8 af[4], bfr[4];
        #pragma unroll
        for (int mi = 0; mi < 4; mi++)
            af[mi] = *(const bf16x8*)&As[(wm + mi*16 + l15)*32 + ((quad ^ swf)*8)];
        #pragma unroll
        for (int ni = 0; ni < 4; ni++)
            bfr[ni] = *(const bf16x8*)&Bs[(wn + ni*16 + l15)*32 + ((quad ^ swf)*8)];
        #pragma unroll
        for (int mi = 0; mi < 4; mi++)
            #pragma unroll
            for (int ni = 0; ni < 4; ni++)
                acc[mi][ni] = __builtin_amdgcn_mfma_f32_16x16x32_bf16(
                    af[mi], bfr[ni], acc[mi][ni], 0, 0, 0);
        __syncthreads();
    }
    #pragma unroll
    for (int mi = 0; mi < 4; mi++)
        #pragma unroll
        for (int ni = 0; ni < 4; ni++) {
            int col = n0 + wn + ni*16 + l15;
            #pragma unroll
            for (int r = 0; r < 4; r++) {
                int row = m0 + wm + mi*16 + quad*4 + r;
                Cb[(size_t)row*Ncols + col] = acc[mi][ni][r];
            }
        }
}

// ------ K3b: y-diagonal 3-tap * rnrm + fuse conv #1 -------------------------
__global__ __launch_bounds__(256) void k_fuse_a2(const float* __restrict__ T,
    const float* __restrict__ rnrm, const float* __restrict__ fw,
    float* __restrict__ Y1)
{
    __shared__ float Sl[10][260];
    int bi = blockIdx.z;
    int p0 = blockIdx.y*8, q0 = blockIdx.x*256;
    const float* Tb = T + (size_t)bi*KL*KL;
    const float* rn = rnrm + bi*KL;
    int t = threadIdx.x;
    for (int i = t; i < 10*258; i += 256) {
        int r = i / 258, c = i - r*258;
        int pp = p0 - 1 + r, qq = q0 - 1 + c;
        float s = 0.f;
        if ((unsigned)pp < KL && (unsigned)qq < KL) {
            size_t base = (size_t)pp*KL + qq;
            float acc = Tb[base];
            if (pp >= KHS && qq >= KHS)           acc += Tb[base - OFFY];
            if (pp < KL - KHS && qq < KL - KHS)   acc += Tb[base + OFFY];
            s = acc * rn[qq];
        }
        Sl[r][c] = s;
    }
    __syncthreads();
    float w[9];
    #pragma unroll
    for (int i = 0; i < 9; i++) w[i] = fw[i];
    int c = t, q = q0 + c;
    float h0[10], h1[10], h2[10];
    #pragma unroll
    for (int r = 0; r < 10; r++) {
        float s0 = Sl[r][c], s1 = Sl[r][c+1], s2 = Sl[r][c+2];
        h0[r] = w[0]*s0 + w[1]*s1 + w[2]*s2;
        h1[r] = w[3]*s0 + w[4]*s1 + w[5]*s2;
        h2[r] = w[6]*s0 + w[7]*s1 + w[8]*s2;
    }
    #pragma unroll
    for (int rr = 0; rr < 8; rr++) {
        Y1[((size_t)bi*KL + p0 + rr)*KL + q] = h0[rr] + h1[rr+1] + h2[rr+2];
    }
}

// ------ K5 v3: fuse conv #2 (transposed flat) + softmax -> bf16 -------------
// 2 output rows per block; 4 shared LDS rows (36.9 KB -> 4 blocks/CU).
// Each output row owned by a 2-wave half (18 chunks of 128 lanes).
__global__ __launch_bounds__(256) void k_fuse_b(const float* __restrict__ Y1,
    const float* __restrict__ fw, const float* __restrict__ mm,
    unsigned short* __restrict__ Ybf)
{
    __shared__ float rowb[4][KL];   // 36864 B
    __shared__ float red[8];
    int blk = blockIdx.x;           // nb*1152
    int tp0 = (blk % 1152)*2;
    int bi  = blk / 1152;
    int t = threadIdx.x;
    const float* Yb = Y1 + (size_t)bi*KL*KL;
    #pragma unroll
    for (int a = 0; a < 4; a++) {
        int t2 = tp0 - 1 + a;
        float4* dst = (float4*)&rowb[a][0];
        if ((unsigned)t2 < KL) {
            int pr = (t2 % KHS)*KHS + t2/KHS;
            const float4* src = (const float4*)&Yb[(size_t)pr*KL];
            for (int i = t; i < KL/4; i += 256) dst[i] = src[i];
        } else {
            float4 z = {0.f,0.f,0.f,0.f};
            for (int i = t; i < KL/4; i += 256) dst[i] = z;
        }
    }
    float w9[9];
    #pragma unroll
    for (int i = 0; i < 9; i++) w9[i] = fw[i];
    __syncthreads();
    int w = t >> 6, lane = t & 63;
    int half = w >> 1;              // which of 2 output rows
    int l128 = t & 127;             // lane within the 2-wave half
    int tp = tp0 + half;
    int x = tp / KHS, y = tp - x*KHS;   // tp = x*48 + y
    int p = y*KHS + x;
    const float* mmb = mm + bi*KL;
    float vals[18];
    float lmax = -1e30f;
    for (int i = 0; i < 18; i++) {
        int q = l128 + i*128;
        int v = q / KHS, u = q - v*KHS;
        int tq = u*KHS + v;
        float acc = 0.f;
        #pragma unroll
        for (int b = 0; b < 3; b++) {
            int s2 = tq + b - 1;
            if ((unsigned)s2 >= KL) continue;
            int qr = (s2 % KHS)*KHS + s2/KHS;
            acc += w9[b]*rowb[half][qr] + w9[3+b]*rowb[half+1][qr]
                 + w9[6+b]*rowb[half+2][qr];
        }
        float val = acc * mmb[q] * 10.0f;
        vals[i] = val;
        lmax = fmaxf(lmax, val);
    }
    #pragma unroll
    for (int off = 32; off > 0; off >>= 1) lmax = fmaxf(lmax, __shfl_down(lmax, off));
    if (lane == 0) red[w] = lmax;
    __syncthreads();
    lmax = fmaxf(red[half*2], red[half*2 + 1]);
    float lsum = 0.f;
    #pragma unroll
    for (int i = 0; i < 18; i++) {
        float e = __expf(vals[i] - lmax);
        vals[i] = e;
        lsum += e;
    }
    #pragma unroll
    for (int off = 32; off > 0; off >>= 1) lsum += __shfl_down(lsum, off);
    if (lane == 0) red[4 + w] = lsum;
    __syncthreads();
    lsum = red[4 + half*2] + red[4 + half*2 + 1];
    float inv = 1.0f / lsum;
    unsigned short* orow = Ybf + ((size_t)bi*KL + p)*KL;
    for (int i = 0; i < 18; i++) {
        int q = l128 + i*128;
        orow[q] = f2bf(vals[i]*inv*mmb[q]);
    }
}

// ---------------- KR: Rt[n][k] bf16, n=(ky,kx,c), k=q -----------------------
__global__ __launch_bounds__(256) void k_buildRt(const float* __restrict__ bsrc,
    unsigned short* __restrict__ Rt)
{
    int idx = blockIdx.x*256 + threadIdx.x;   // nb*1024*288
    int k8 = idx % 288;
    int rest = idx / 288;
    int n  = rest % 1024;
    int bi = rest / 1024;
    int jj = n >> 6, c = n & 63;
    int ky = jj >> 2, kx = jj & 3;
    int k0 = k8*8;
    bf16x8 vv;
    #pragma unroll
    for (int j = 0; j < 8; j++) {
        int q = k0 + j;
        int v = q / KHS, u = q % KHS;
        int ry = 2*v + ky - 1, rx = 2*u + kx - 1;
        float val = 0.f;
        if ((unsigned)ry < KHH && (unsigned)rx < KHH)
            val = bsrc[(((size_t)bi*KHH + ry)*KHH + rx)*KC + c];
        vv[j] = (short)f2bf(val);
    }
    *(bf16x8*)&Rt[((size_t)bi*1024 + n)*KL + k0] = vv;
}

// -------- K8: overlap-add (adjoint of stride-2 4x4 SAME conv), sum split-K --
__global__ __launch_bounds__(256) void k_overlap(const float* __restrict__ P,
    float* __restrict__ out, size_t psize)
{
    size_t gid = (size_t)blockIdx.x*256 + threadIdx.x;   // nb*96*96*64
    int c = gid & 63;
    size_t r = gid >> 6;
    int ix = (int)(r % KHH); r /= KHH;
    int iy = (int)(r % KHH);
    int bi = (int)(r / KHH);
    const float* P1 = P + psize;
    float acc = 0.f;
    #pragma unroll
    for (int sy = 0; sy < 2; sy++) {
        int ky = (iy & 1) ? (sy*2) : (sy*2 + 1);
        int yp = (iy + 1 - ky) >> 1;
        if ((unsigned)yp >= KHS) continue;
        #pragma unroll
        for (int sx = 0; sx < 2; sx++) {
            int kx = (ix & 1) ? (sx*2) : (sx*2 + 1);
            int xp = (ix + 1 - kx) >> 1;
            if ((unsigned)xp >= KHS) continue;
            size_t idx = (((size_t)bi*KL + yp*KHS + xp)*16 + (ky*4 + kx))*64 + c;
            acc += P[idx] + P1[idx];
        }
    }
    out[gid] = 0.25f * acc;
}

extern "C" void kernel_launch(void* const* d_in, const int* in_sizes, int n_in,
                              void* d_out, int out_size, void* d_ws, size_t ws_size,
                              hipStream_t stream)
{
    const float* f    = (const float*)d_in[0];
    const float* b    = (const float*)d_in[1];
    const float* mask = (const float*)d_in[2];
    const float* fw   = (const float*)d_in[3];
    float* out = (float*)d_out;

    auto need = [](int nbc) -> size_t {
        return (size_t)nbc * (2ull*KL*KC + 4ull*KL + 2ull*(size_t)KL*KL) * 4ull;
    };
    int nbc = 4;
    if (need(nbc) > ws_size) nbc = 2;
    if (need(nbc) > ws_size) nbc = 1;

    for (int bi0 = 0; bi0 < 4; bi0 += nbc) {
        int nb = (4 - bi0 < nbc) ? (4 - bi0) : nbc;
        const float* fc = f    + (size_t)bi0*KHH*KHH*KC;
        const float* bc = b    + (size_t)bi0*KHH*KHH*KC;
        const float* mc = mask + (size_t)bi0*KHH*KHH;
        float* outc = out + (size_t)bi0*KHH*KHH*KC;

        float* w    = (float*)d_ws;
        float* fd   = w;  w += (size_t)nbc*KL*KC;
        float* bd   = w;  w += (size_t)nbc*KL*KC;
        float* nbuf = w;  w += (size_t)nbc*KL;
        float* mdd  = w;  w += (size_t)nbc*KL;
        float* rnrm = w;  w += (size_t)nbc*KL;
        float* mmb  = w;  w += (size_t)nbc*KL;
        float* bufA = w;  w += (size_t)nbc*KL*KL;
        float* bufB = w;
        // lifetimes:
        //  bufB: [Ahat|Bhat] (bf16) -> Y1 (fp32) -> [P0|P1] (fp32)
        //  bufA: T (fp32) -> [Ybf bf16 | Rt bf16]
        unsigned short* Ahat = (unsigned short*)bufB;
        unsigned short* Bhat = Ahat + (size_t)nbc*KL*576;
        float* Tbuf = bufA;
        float* Y1   = bufB;
        unsigned short* Ybf = (unsigned short*)bufA;
        unsigned short* Rtb = Ybf + (size_t)nbc*KL*KL;
        float* Pbuf = bufB;
        size_t psize = (size_t)nbc*KL*1024;   // one split-K partial

        k_prep      <<<nb*KL, 64, 0, stream>>>(fc, bc, mc, fd, bd, nbuf, mdd);
        k_normmask  <<<(nb*KL)/256, 256, 0, stream>>>(nbuf, mdd, rnrm, mmb);
        k_build_hilo<<<nb*KL, 64, 0, stream>>>(fd, bd, Ahat, Bhat);
        // T = Ahat * Bhat^T  (K=576, no split)
        k_mfma_bt<18><<<dim3(18, 18, nb), 256, 0, stream>>>(
            Ahat, Bhat, Tbuf, KL, (size_t)KL*576, (size_t)KL*576, (size_t)KL*KL,
            576, 1, 0);
        // y-diag 3-tap * rnrm + fuse1: T (bufA) -> Y1 (bufB)
        k_fuse_a2   <<<dim3(9, 288, nb), 256, 0, stream>>>(Tbuf, rnrm, fw, Y1);
        // fuse2 + softmax: Y1 (bufB) -> Ybf (bufA)
        k_fuse_b    <<<nb*1152, 256, 0, stream>>>(Y1, fw, mmb, Ybf);
        k_buildRt   <<<(nb*1024*288)/256, 256, 0, stream>>>(bc, Rtb);
        // P = Ybf * Rt^T (K=2304, split-K=2 -> P0,P1)
        k_mfma_bt<36><<<dim3(8, 18, nb*2), 256, 0, stream>>>(
            Ybf, Rtb, Pbuf, 1024, (size_t)KL*KL, (size_t)1024*KL, (size_t)KL*1024,
            2304, 2, psize);
        k_overlap   <<<nb*KL, 256, 0, stream>>>(Pbuf, outc, psize);
    }
}

// Round 9
// 383.627 us; speedup vs baseline: 1.2506x; 1.0647x over previous
//
#include <hip/hip_runtime.h>
#include <hip/hip_bf16.h>

#define KL  2304   // 48*48
#define KC  64
#define KHS 48
#define KHH 96
#define OFFY (KHS*(KL + 1))    // flat offset for (p+48,q+48)

typedef __attribute__((ext_vector_type(8))) short bf16x8;
typedef __attribute__((ext_vector_type(4))) short bf16x4;
typedef __attribute__((ext_vector_type(4))) float f32x4;

static __device__ inline unsigned short f2bf(float x) {
    __hip_bfloat16 h = __float2bfloat16(x);
    return *reinterpret_cast<unsigned short*>(&h);
}
static __device__ inline float bf2f(unsigned short u) {
    unsigned v = ((unsigned)u) << 16;
    return __uint_as_float(v);
}

// ---- K0': downsample + |bd|^2 + mask + split-bf16 x-shift operands ---------
// One block per (bi,p), 64 threads = channels. Writes Ahat/Bhat (K=576
// layout: k = seg*192 + dxi*64 + c), nbuf, mdd. fd/bd never materialized.
__global__ __launch_bounds__(64) void k_prep2(const float* __restrict__ f,
    const float* __restrict__ bsrc, const float* __restrict__ mask,
    float* __restrict__ nbuf, float* __restrict__ mdd,
    unsigned short* __restrict__ Ahat, unsigned short* __restrict__ Bhat)
{
    int blk = blockIdx.x;              // nb*KL blocks
    int p = blk % KL, bi = blk / KL;
    int y = p / KHS, x = p % KHS;
    int fy = 2*y + 1;
    int c = threadIdx.x;
    unsigned short* Ap = Ahat + ((size_t)bi*KL + p)*576;
    unsigned short* Bp = Bhat + ((size_t)bi*KL + p)*576;
    float bc = 0.f;
    #pragma unroll
    for (int dxi = 0; dxi < 3; dxi++) {
        int xx = x + dxi - 1;
        float av = 0.f, bv = 0.f;
        if ((unsigned)xx < KHS) {
            int fxx = 2*xx + 1;
            size_t src = (((size_t)bi*KHH + fy)*KHH + fxx)*KC + c;
            av = f[src]; bv = bsrc[src];
        }
        if (dxi == 1) bc = bv;
        unsigned short ah = f2bf(av);
        unsigned short al = f2bf(av - bf2f(ah));
        unsigned short bh = f2bf(bv);
        unsigned short bl = f2bf(bv - bf2f(bh));
        Ap[0*192 + dxi*64 + c] = ah;
        Ap[1*192 + dxi*64 + c] = ah;
        Ap[2*192 + dxi*64 + c] = al;
        Bp[0*192 + dxi*64 + c] = bh;
        Bp[1*192 + dxi*64 + c] = bl;
        Bp[2*192 + dxi*64 + c] = bh;
    }
    float s = bc*bc;
    #pragma unroll
    for (int off = 32; off > 0; off >>= 1) s += __shfl_down(s, off);
    if (c == 0) {
        nbuf[bi*KL + p] = s;
        mdd[bi*KL + p]  = mask[((size_t)bi*KHH + fy)*KHH + (2*x + 1)];
    }
}

// ------- K1: rnrm[q] = 1/max(sqrt(9-tap sum nb),1e-4); mm from mask --------
__global__ __launch_bounds__(256) void k_normmask(const float* __restrict__ nbuf,
    const float* __restrict__ mdd, float* __restrict__ rnrm, float* __restrict__ mm)
{
    int i = blockIdx.x*256 + threadIdx.x;   // nb*KL
    int q = i % KL, bi = i / KL;
    int v = q / KHS, u = q % KHS;
    float sn = 0.f, sm = 0.f;
    for (int dy = -1; dy <= 1; dy++) {
        int vv = v + dy; if ((unsigned)vv >= KHS) continue;
        for (int dx = -1; dx <= 1; dx++) {
            int uu = u + dx; if ((unsigned)uu >= KHS) continue;
            sn += nbuf[bi*KL + vv*KHS + uu];
            sm += mdd[bi*KL + vv*KHS + uu];
        }
    }
    rnrm[i] = 1.0f / fmaxf(sqrtf(sn), 1e-4f);
    mm[i]   = (sm == 0.0f) ? 1.0f : 0.0f;
}

// ------ MFMA GEMM: C = A * B^T, optional split-K, fp32 or bf16 output -------
template<int KITERS, bool OUTBF16>
__global__ __launch_bounds__(256) void k_mfma_bt(const unsigned short* __restrict__ A,
    const unsigned short* __restrict__ B, void* __restrict__ Cv,
    int Ncols, size_t sA, size_t sB, size_t sC, int KDIM, int nsplit, size_t psize)
{
    int z = blockIdx.z;
    int ks = z % nsplit, bi = z / nsplit;
    int kbase = ks * KITERS * 32;
    int n0 = blockIdx.x*128, m0 = blockIdx.y*128;
    const unsigned short* Ab = A + (size_t)bi*sA;
    const unsigned short* Bb = B + (size_t)bi*sB;
    __shared__ unsigned short As[128*32];
    __shared__ unsigned short Bs[128*32];
    int t = threadIdx.x;
    int lane = t & 63, w = t >> 6;
    int l15 = lane & 15, quad = lane >> 4;
    int swf = (l15 >> 2) & 3;
    int wm = (w >> 1)*64, wn = (w & 1)*64;
    int srow = lane >> 2;
    int ch = lane & 3;
    f32x4 acc[4][4];
    #pragma unroll
    for (int i = 0; i < 4; i++)
        #pragma unroll
        for (int j = 0; j < 4; j++) acc[i][j] = (f32x4){0.f,0.f,0.f,0.f};

    for (int kk = 0; kk < KITERS; kk++) {
        int k0 = kbase + kk*32;
        #pragma unroll
        for (int i = 0; i < 2; i++) {
            int rbase = w*32 + i*16;
            int r = rbase + srow;
            int cs = (ch ^ ((r >> 2) & 3))*8;
            const unsigned short* ga = &Ab[(size_t)(m0 + r)*KDIM + k0 + cs];
            __builtin_amdgcn_global_load_lds(
                (const __attribute__((address_space(1))) void*)ga,
                (__attribute__((address_space(3))) void*)&As[rbase*32], 16, 0, 0);
            const unsigned short* gb = &Bb[(size_t)(n0 + r)*KDIM + k0 + cs];
            __builtin_amdgcn_global_load_lds(
                (const __attribute__((address_space(1))) void*)gb,
                (__attribute__((address_space(3))) void*)&Bs[rbase*32], 16, 0, 0);
        }
        __syncthreads();
        bf16x8 af[4], bfr[4];
        #pragma unroll
        for (int mi = 0; mi < 4; mi++)
            af[mi] = *(const bf16x8*)&As[(wm + mi*16 + l15)*32 + ((quad ^ swf)*8)];
        #pragma unroll
        for (int ni = 0; ni < 4; ni++)
            bfr[ni] = *(const bf16x8*)&Bs[(wn + ni*16 + l15)*32 + ((quad ^ swf)*8)];
        #pragma unroll
        for (int mi = 0; mi < 4; mi++)
            #pragma unroll
            for (int ni = 0; ni < 4; ni++)
                acc[mi][ni] = __builtin_amdgcn_mfma_f32_16x16x32_bf16(
                    af[mi], bfr[ni], acc[mi][ni], 0, 0, 0);
        __syncthreads();
    }
    if (OUTBF16) {
        unsigned short* Cb = (unsigned short*)Cv + (size_t)ks*psize + (size_t)bi*sC;
        #pragma unroll
        for (int mi = 0; mi < 4; mi++)
            #pragma unroll
            for (int ni = 0; ni < 4; ni++) {
                int col = n0 + wn + ni*16 + l15;
                #pragma unroll
                for (int r = 0; r < 4; r++) {
                    int row = m0 + wm + mi*16 + quad*4 + r;
                    Cb[(size_t)row*Ncols + col] = f2bf(acc[mi][ni][r]);
                }
            }
    } else {
        float* Cb = (float*)Cv + (size_t)ks*psize + (size_t)bi*sC;
        #pragma unroll
        for (int mi = 0; mi < 4; mi++)
            #pragma unroll
            for (int ni = 0; ni < 4; ni++) {
                int col = n0 + wn + ni*16 + l15;
                #pragma unroll
                for (int r = 0; r < 4; r++) {
                    int row = m0 + wm + mi*16 + quad*4 + r;
                    Cb[(size_t)row*Ncols + col] = acc[mi][ni][r];
                }
            }
    }
}

// ------ K3b v2: y-diagonal 3-tap * rnrm + fuse conv #1 ----------------------
// Halo tile 10 x 264 (cols qq = q0-4 .. q0+259), f32x4 branch-free fill for
// interior q-tiles; scalar guarded fill for edge tiles (qt 0 and 8).
__global__ __launch_bounds__(256) void k_fuse_a2(const float* __restrict__ T,
    const float* __restrict__ rnrm, const float* __restrict__ fw,
    float* __restrict__ Y1)
{
    __shared__ float Sl[10][272];
    int bi = blockIdx.z;
    int qt = blockIdx.x;
    int p0 = blockIdx.y*8, q0 = qt*256;
    const float* Tb = T + (size_t)bi*KL*KL;
    const float* rn = rnrm + bi*KL;
    int t = threadIdx.x;
    bool edge = (qt == 0) | (qt == 8);
    if (!edge) {
        for (int idx = t; idx < 10*66; idx += 256) {
            int r = idx / 66, j = idx - r*66;
            int pp = p0 - 1 + r;
            int qq0 = q0 - 4 + j*4;
            f32x4 s = (f32x4){0.f,0.f,0.f,0.f};
            if ((unsigned)pp < KL) {
                size_t base = (size_t)pp*KL + qq0;
                bool bm = (pp >= KHS), bp = (pp < KL - KHS);
                size_t offm = bm ? (size_t)OFFY : 0;
                size_t offp = bp ? (size_t)OFFY : 0;
                float fm = bm ? 1.f : 0.f, fp2 = bp ? 1.f : 0.f;
                f32x4 v0 = *(const f32x4*)&Tb[base];
                f32x4 vm = *(const f32x4*)&Tb[base - offm];
                f32x4 vp = *(const f32x4*)&Tb[base + offp];
                f32x4 rv = *(const f32x4*)&rn[qq0];
                s = (v0 + fm*vm + fp2*vp) * rv;
            }
            *(f32x4*)&Sl[r][j*4] = s;
        }
    } else {
        for (int idx = t; idx < 10*264; idx += 256) {
            int r = idx / 264, c = idx - r*264;
            int pp = p0 - 1 + r, qq = q0 - 4 + c;
            float s = 0.f;
            if ((unsigned)pp < KL && (unsigned)qq < KL) {
                size_t base = (size_t)pp*KL + qq;
                float acc = Tb[base];
                if (pp >= KHS && qq >= KHS)         acc += Tb[base - OFFY];
                if (pp < KL - KHS && qq < KL - KHS) acc += Tb[base + OFFY];
                s = acc * rn[qq];
            }
            Sl[r][c] = s;
        }
    }
    __syncthreads();
    float w[9];
    #pragma unroll
    for (int i = 0; i < 9; i++) w[i] = fw[i];
    int q = q0 + t;
    float h0[10], h1[10], h2[10];
    #pragma unroll
    for (int r = 0; r < 10; r++) {
        float s0 = Sl[r][t+3], s1 = Sl[r][t+4], s2 = Sl[r][t+5];
        h0[r] = w[0]*s0 + w[1]*s1 + w[2]*s2;
        h1[r] = w[3]*s0 + w[4]*s1 + w[5]*s2;
        h2[r] = w[6]*s0 + w[7]*s1 + w[8]*s2;
    }
    #pragma unroll
    for (int rr = 0; rr < 8; rr++) {
        Y1[((size_t)bi*KL + p0 + rr)*KL + q] = h0[rr] + h1[rr+1] + h2[rr+2];
    }
}

// ------ K5 v3: fuse conv #2 (transposed flat) + softmax -> bf16 -------------
__global__ __launch_bounds__(256) void k_fuse_b(const float* __restrict__ Y1,
    const float* __restrict__ fw, const float* __restrict__ mm,
    unsigned short* __restrict__ Ybf)
{
    __shared__ float rowb[4][KL];   // 36864 B
    __shared__ float red[8];
    int blk = blockIdx.x;           // nb*1152
    int tp0 = (blk % 1152)*2;
    int bi  = blk / 1152;
    int t = threadIdx.x;
    const float* Yb = Y1 + (size_t)bi*KL*KL;
    #pragma unroll
    for (int a = 0; a < 4; a++) {
        int t2 = tp0 - 1 + a;
        float4* dst = (float4*)&rowb[a][0];
        if ((unsigned)t2 < KL) {
            int pr = (t2 % KHS)*KHS + t2/KHS;
            const float4* src = (const float4*)&Yb[(size_t)pr*KL];
            for (int i = t; i < KL/4; i += 256) dst[i] = src[i];
        } else {
            float4 z = {0.f,0.f,0.f,0.f};
            for (int i = t; i < KL/4; i += 256) dst[i] = z;
        }
    }
    float w9[9];
    #pragma unroll
    for (int i = 0; i < 9; i++) w9[i] = fw[i];
    __syncthreads();
    int w = t >> 6, lane = t & 63;
    int half = w >> 1;
    int l128 = t & 127;
    int tp = tp0 + half;
    int x = tp / KHS, y = tp - x*KHS;   // tp = x*48 + y
    int p = y*KHS + x;
    const float* mmb = mm + bi*KL;
    float vals[18];
    float lmax = -1e30f;
    for (int i = 0; i < 18; i++) {
        int q = l128 + i*128;
        int v = q / KHS, u = q - v*KHS;
        int tq = u*KHS + v;
        float acc = 0.f;
        #pragma unroll
        for (int b = 0; b < 3; b++) {
            int s2 = tq + b - 1;
            if ((unsigned)s2 >= KL) continue;
            int qr = (s2 % KHS)*KHS + s2/KHS;
            acc += w9[b]*rowb[half][qr] + w9[3+b]*rowb[half+1][qr]
                 + w9[6+b]*rowb[half+2][qr];
        }
        float val = acc * mmb[q] * 10.0f;
        vals[i] = val;
        lmax = fmaxf(lmax, val);
    }
    #pragma unroll
    for (int off = 32; off > 0; off >>= 1) lmax = fmaxf(lmax, __shfl_down(lmax, off));
    if (lane == 0) red[w] = lmax;
    __syncthreads();
    lmax = fmaxf(red[half*2], red[half*2 + 1]);
    float lsum = 0.f;
    #pragma unroll
    for (int i = 0; i < 18; i++) {
        float e = __expf(vals[i] - lmax);
        vals[i] = e;
        lsum += e;
    }
    #pragma unroll
    for (int off = 32; off > 0; off >>= 1) lsum += __shfl_down(lsum, off);
    if (lane == 0) red[4 + w] = lsum;
    __syncthreads();
    lsum = red[4 + half*2] + red[4 + half*2 + 1];
    float inv = 1.0f / lsum;
    unsigned short* orow = Ybf + ((size_t)bi*KL + p)*KL;
    for (int i = 0; i < 18; i++) {
        int q = l128 + i*128;
        orow[q] = f2bf(vals[i]*inv*mmb[q]);
    }
}

// ---------------- KR: Rt[n][k] bf16, n=(ky,kx,c), k=q -----------------------
__global__ __launch_bounds__(256) void k_buildRt(const float* __restrict__ bsrc,
    unsigned short* __restrict__ Rt)
{
    int idx = blockIdx.x*256 + threadIdx.x;   // nb*1024*288
    int k8 = idx % 288;
    int rest = idx / 288;
    int n  = rest % 1024;
    int bi = rest / 1024;
    int jj = n >> 6, c = n & 63;
    int ky = jj >> 2, kx = jj & 3;
    int k0 = k8*8;
    bf16x8 vv;
    #pragma unroll
    for (int j = 0; j < 8; j++) {
        int q = k0 + j;
        int v = q / KHS, u = q % KHS;
        int ry = 2*v + ky - 1, rx = 2*u + kx - 1;
        float val = 0.f;
        if ((unsigned)ry < KHH && (unsigned)rx < KHH)
            val = bsrc[(((size_t)bi*KHH + ry)*KHH + rx)*KC + c];
        vv[j] = (short)f2bf(val);
    }
    *(bf16x8*)&Rt[((size_t)bi*1024 + n)*KL + k0] = vv;
}

// -------- K8: overlap-add over 3 bf16 split-K partials, 4 channels/thread ---
__global__ __launch_bounds__(256) void k_overlap(const unsigned short* __restrict__ P,
    float* __restrict__ out, size_t psize)
{
    size_t gid = (size_t)blockIdx.x*256 + threadIdx.x;   // nb*96*96*16
    int c4 = (int)(gid & 15)*4;
    size_t r = gid >> 4;
    int ix = (int)(r % KHH); r /= KHH;
    int iy = (int)(r % KHH);
    int bi = (int)(r / KHH);
    f32x4 acc = (f32x4){0.f,0.f,0.f,0.f};
    #pragma unroll
    for (int sy = 0; sy < 2; sy++) {
        int ky = (iy & 1) ? (sy*2) : (sy*2 + 1);
        int yp = (iy + 1 - ky) >> 1;
        if ((unsigned)yp >= KHS) continue;
        #pragma unroll
        for (int sx = 0; sx < 2; sx++) {
            int kx = (ix & 1) ? (sx*2) : (sx*2 + 1);
            int xp = (ix + 1 - kx) >> 1;
            if ((unsigned)xp >= KHS) continue;
            size_t idx = (((size_t)bi*KL + yp*KHS + xp)*16 + (ky*4 + kx))*64 + c4;
            #pragma unroll
            for (int s = 0; s < 3; s++) {
                bf16x4 v = *(const bf16x4*)&P[idx + s*psize];
                #pragma unroll
                for (int j = 0; j < 4; j++)
                    acc[j] += bf2f((unsigned short)v[j]);
            }
        }
    }
    f32x4 o = acc * 0.25f;
    *(f32x4*)&out[(((size_t)bi*KHH + iy)*KHH + ix)*KC + c4] = o;
}

extern "C" void kernel_launch(void* const* d_in, const int* in_sizes, int n_in,
                              void* d_out, int out_size, void* d_ws, size_t ws_size,
                              hipStream_t stream)
{
    const float* f    = (const float*)d_in[0];
    const float* b    = (const float*)d_in[1];
    const float* mask = (const float*)d_in[2];
    const float* fw   = (const float*)d_in[3];
    float* out = (float*)d_out;

    auto need = [](int nbc) -> size_t {
        return (size_t)nbc * (2ull*KL*KC + 4ull*KL + 2ull*(size_t)KL*KL) * 4ull;
    };
    int nbc = 4;
    if (need(nbc) > ws_size) nbc = 2;
    if (need(nbc) > ws_size) nbc = 1;

    for (int bi0 = 0; bi0 < 4; bi0 += nbc) {
        int nb = (4 - bi0 < nbc) ? (4 - bi0) : nbc;
        const float* fc = f    + (size_t)bi0*KHH*KHH*KC;
        const float* bc = b    + (size_t)bi0*KHH*KHH*KC;
        const float* mc = mask + (size_t)bi0*KHH*KHH;
        float* outc = out + (size_t)bi0*KHH*KHH*KC;

        float* w    = (float*)d_ws;
        float* nbuf = w;  w += (size_t)nbc*KL;
        float* mdd  = w;  w += (size_t)nbc*KL;
        float* rnrm = w;  w += (size_t)nbc*KL;
        float* mmb  = w;  w += (size_t)nbc*KL;
        float* bufA = w;  w += (size_t)nbc*KL*KL;
        float* bufB = w;
        // lifetimes:
        //  bufB: [Ahat|Bhat] (bf16, 21.2 MB) -> Y1 (fp32, 84.9) -> P0..P2 (bf16, 56.6)
        //  bufA: T (fp32) -> [Ybf bf16 | Rt bf16]
        unsigned short* Ahat = (unsigned short*)bufB;
        unsigned short* Bhat = Ahat + (size_t)nbc*KL*576;
        float* Tbuf = bufA;
        float* Y1   = bufB;
        unsigned short* Ybf = (unsigned short*)bufA;
        unsigned short* Rtb = Ybf + (size_t)nbc*KL*KL;
        unsigned short* Pbuf = (unsigned short*)bufB;
        size_t psize = (size_t)nbc*KL*1024;   // one split-K partial (elements)

        k_prep2     <<<nb*KL, 64, 0, stream>>>(fc, bc, mc, nbuf, mdd, Ahat, Bhat);
        k_normmask  <<<(nb*KL)/256, 256, 0, stream>>>(nbuf, mdd, rnrm, mmb);
        // T = Ahat * Bhat^T  (K=576, no split, fp32 out)
        k_mfma_bt<18,false><<<dim3(18, 18, nb), 256, 0, stream>>>(
            Ahat, Bhat, Tbuf, KL, (size_t)KL*576, (size_t)KL*576, (size_t)KL*KL,
            576, 1, 0);
        // y-diag 3-tap * rnrm + fuse1: T (bufA) -> Y1 (bufB)
        k_fuse_a2   <<<dim3(9, 288, nb), 256, 0, stream>>>(Tbuf, rnrm, fw, Y1);
        // fuse2 + softmax: Y1 (bufB) -> Ybf (bufA)
        k_fuse_b    <<<nb*1152, 256, 0, stream>>>(Y1, fw, mmb, Ybf);
        k_buildRt   <<<(nb*1024*288)/256, 256, 0, stream>>>(bc, Rtb);
        // P = Ybf * Rt^T (K=2304, split-K=3, bf16 partials P0..P2)
        k_mfma_bt<24,true><<<dim3(8, 18, nb*3), 256, 0, stream>>>(
            Ybf, Rtb, Pbuf, 1024, (size_t)KL*KL, (size_t)1024*KL, (size_t)KL*1024,
            2304, 3, psize);
        k_overlap   <<<nb*KL/4*16/16, 256, 0, stream>>>(Pbuf, outc, psize);
    }
}

// Round 10
// 339.637 us; speedup vs baseline: 1.4126x; 1.1295x over previous
//
#include <hip/hip_runtime.h>
#include <hip/hip_bf16.h>

#define KL  2304   // 48*48
#define KC  64
#define KHS 48
#define KHH 96
#define OFFY (KHS*(KL + 1))    // flat offset for (p+48,q+48)

typedef __attribute__((ext_vector_type(8))) short bf16x8;
typedef __attribute__((ext_vector_type(4))) short bf16x4;
typedef __attribute__((ext_vector_type(4))) float f32x4;

static __device__ inline unsigned short f2bf(float x) {
    __hip_bfloat16 h = __float2bfloat16(x);
    return *reinterpret_cast<unsigned short*>(&h);
}
static __device__ inline float bf2f(unsigned short u) {
    unsigned v = ((unsigned)u) << 16;
    return __uint_as_float(v);
}

// ---- K0': downsample + |bd|^2 + mask + split-bf16 x-shift operands ---------
__global__ __launch_bounds__(64) void k_prep2(const float* __restrict__ f,
    const float* __restrict__ bsrc, const float* __restrict__ mask,
    float* __restrict__ nbuf, float* __restrict__ mdd,
    unsigned short* __restrict__ Ahat, unsigned short* __restrict__ Bhat)
{
    int blk = blockIdx.x;              // nb*KL blocks
    int p = blk % KL, bi = blk / KL;
    int y = p / KHS, x = p % KHS;
    int fy = 2*y + 1;
    int c = threadIdx.x;
    unsigned short* Ap = Ahat + ((size_t)bi*KL + p)*576;
    unsigned short* Bp = Bhat + ((size_t)bi*KL + p)*576;
    float bc = 0.f;
    #pragma unroll
    for (int dxi = 0; dxi < 3; dxi++) {
        int xx = x + dxi - 1;
        float av = 0.f, bv = 0.f;
        if ((unsigned)xx < KHS) {
            int fxx = 2*xx + 1;
            size_t src = (((size_t)bi*KHH + fy)*KHH + fxx)*KC + c;
            av = f[src]; bv = bsrc[src];
        }
        if (dxi == 1) bc = bv;
        unsigned short ah = f2bf(av);
        unsigned short al = f2bf(av - bf2f(ah));
        unsigned short bh = f2bf(bv);
        unsigned short bl = f2bf(bv - bf2f(bh));
        Ap[0*192 + dxi*64 + c] = ah;
        Ap[1*192 + dxi*64 + c] = ah;
        Ap[2*192 + dxi*64 + c] = al;
        Bp[0*192 + dxi*64 + c] = bh;
        Bp[1*192 + dxi*64 + c] = bl;
        Bp[2*192 + dxi*64 + c] = bh;
    }
    float s = bc*bc;
    #pragma unroll
    for (int off = 32; off > 0; off >>= 1) s += __shfl_down(s, off);
    if (c == 0) {
        nbuf[bi*KL + p] = s;
        mdd[bi*KL + p]  = mask[((size_t)bi*KHH + fy)*KHH + (2*x + 1)];
    }
}

// ------- K1: rnrm[q] = 1/max(sqrt(9-tap sum nb),1e-4); mm from mask --------
__global__ __launch_bounds__(256) void k_normmask(const float* __restrict__ nbuf,
    const float* __restrict__ mdd, float* __restrict__ rnrm, float* __restrict__ mm)
{
    int i = blockIdx.x*256 + threadIdx.x;   // nb*KL
    int q = i % KL, bi = i / KL;
    int v = q / KHS, u = q % KHS;
    float sn = 0.f, sm = 0.f;
    for (int dy = -1; dy <= 1; dy++) {
        int vv = v + dy; if ((unsigned)vv >= KHS) continue;
        for (int dx = -1; dx <= 1; dx++) {
            int uu = u + dx; if ((unsigned)uu >= KHS) continue;
            sn += nbuf[bi*KL + vv*KHS + uu];
            sm += mdd[bi*KL + vv*KHS + uu];
        }
    }
    rnrm[i] = 1.0f / fmaxf(sqrtf(sn), 1e-4f);
    mm[i]   = (sm == 0.0f) ? 1.0f : 0.0f;
}

// ------ MFMA GEMM: C = A * B^T, optional split-K, fp32/bf16 out, XCD swizzle
// Block remap: dispatch-flat -> (xcd, slot) -> g = xcd*per + slot, decoded
// with n fastest. Each XCD owns contiguous (bi,ks)-slices so the B-slice
// (~1.5 MB) stays L2-resident and A streams once. Grid total must be %8==0.
template<int KITERS, bool OUTBF16>
__global__ __launch_bounds__(256) void k_mfma_bt(const unsigned short* __restrict__ A,
    const unsigned short* __restrict__ B, void* __restrict__ Cv,
    int Ncols, size_t sA, size_t sB, size_t sC, int KDIM, int nsplit, size_t psize)
{
    int flat = blockIdx.x + gridDim.x*(blockIdx.y + gridDim.y*blockIdx.z);
    int nxy = gridDim.x*gridDim.y;
    int per = (nxy*gridDim.z) >> 3;
    int g = (flat & 7)*per + (flat >> 3);
    int z = g / nxy; int r = g - z*nxy;
    int by = r / gridDim.x; int bx = r - by*gridDim.x;

    int ks = z % nsplit, bi = z / nsplit;
    int kbase = ks * KITERS * 32;
    int n0 = bx*128, m0 = by*128;
    const unsigned short* Ab = A + (size_t)bi*sA;
    const unsigned short* Bb = B + (size_t)bi*sB;
    __shared__ unsigned short As[128*32];
    __shared__ unsigned short Bs[128*32];
    int t = threadIdx.x;
    int lane = t & 63, w = t >> 6;
    int l15 = lane & 15, quad = lane >> 4;
    int swf = (l15 >> 2) & 3;
    int wm = (w >> 1)*64, wn = (w & 1)*64;
    int srow = lane >> 2;
    int ch = lane & 3;
    f32x4 acc[4][4];
    #pragma unroll
    for (int i = 0; i < 4; i++)
        #pragma unroll
        for (int j = 0; j < 4; j++) acc[i][j] = (f32x4){0.f,0.f,0.f,0.f};

    for (int kk = 0; kk < KITERS; kk++) {
        int k0 = kbase + kk*32;
        #pragma unroll
        for (int i = 0; i < 2; i++) {
            int rbase = w*32 + i*16;
            int r2 = rbase + srow;
            int cs = (ch ^ ((r2 >> 2) & 3))*8;
            const unsigned short* ga = &Ab[(size_t)(m0 + r2)*KDIM + k0 + cs];
            __builtin_amdgcn_global_load_lds(
                (const __attribute__((address_space(1))) void*)ga,
                (__attribute__((address_space(3))) void*)&As[rbase*32], 16, 0, 0);
            const unsigned short* gb = &Bb[(size_t)(n0 + r2)*KDIM + k0 + cs];
            __builtin_amdgcn_global_load_lds(
                (const __attribute__((address_space(1))) void*)gb,
                (__attribute__((address_space(3))) void*)&Bs[rbase*32], 16, 0, 0);
        }
        __syncthreads();
        bf16x8 af[4], bfr[4];
        #pragma unroll
        for (int mi = 0; mi < 4; mi++)
            af[mi] = *(const bf16x8*)&As[(wm + mi*16 + l15)*32 + ((quad ^ swf)*8)];
        #pragma unroll
        for (int ni = 0; ni < 4; ni++)
            bfr[ni] = *(const bf16x8*)&Bs[(wn + ni*16 + l15)*32 + ((quad ^ swf)*8)];
        #pragma unroll
        for (int mi = 0; mi < 4; mi++)
            #pragma unroll
            for (int ni = 0; ni < 4; ni++)
                acc[mi][ni] = __builtin_amdgcn_mfma_f32_16x16x32_bf16(
                    af[mi], bfr[ni], acc[mi][ni], 0, 0, 0);
        __syncthreads();
    }
    if (OUTBF16) {
        unsigned short* Cb = (unsigned short*)Cv + (size_t)ks*psize + (size_t)bi*sC;
        #pragma unroll
        for (int mi = 0; mi < 4; mi++)
            #pragma unroll
            for (int ni = 0; ni < 4; ni++) {
                int col = n0 + wn + ni*16 + l15;
                #pragma unroll
                for (int r2 = 0; r2 < 4; r2++) {
                    int row = m0 + wm + mi*16 + quad*4 + r2;
                    Cb[(size_t)row*Ncols + col] = f2bf(acc[mi][ni][r2]);
                }
            }
    } else {
        float* Cb = (float*)Cv + (size_t)ks*psize + (size_t)bi*sC;
        #pragma unroll
        for (int mi = 0; mi < 4; mi++)
            #pragma unroll
            for (int ni = 0; ni < 4; ni++) {
                int col = n0 + wn + ni*16 + l15;
                #pragma unroll
                for (int r2 = 0; r2 < 4; r2++) {
                    int row = m0 + wm + mi*16 + quad*4 + r2;
                    Cb[(size_t)row*Ncols + col] = acc[mi][ni][r2];
                }
            }
    }
}

// ------ K3b v2: y-diagonal 3-tap * rnrm + fuse conv #1 ----------------------
__global__ __launch_bounds__(256) void k_fuse_a2(const float* __restrict__ T,
    const float* __restrict__ rnrm, const float* __restrict__ fw,
    float* __restrict__ Y1)
{
    __shared__ float Sl[10][272];
    int bi = blockIdx.z;
    int qt = blockIdx.x;
    int p0 = blockIdx.y*8, q0 = qt*256;
    const float* Tb = T + (size_t)bi*KL*KL;
    const float* rn = rnrm + bi*KL;
    int t = threadIdx.x;
    bool edge = (qt == 0) | (qt == 8);
    if (!edge) {
        for (int idx = t; idx < 10*66; idx += 256) {
            int r = idx / 66, j = idx - r*66;
            int pp = p0 - 1 + r;
            int qq0 = q0 - 4 + j*4;
            f32x4 s = (f32x4){0.f,0.f,0.f,0.f};
            if ((unsigned)pp < KL) {
                size_t base = (size_t)pp*KL + qq0;
                bool bm = (pp >= KHS), bp = (pp < KL - KHS);
                size_t offm = bm ? (size_t)OFFY : 0;
                size_t offp = bp ? (size_t)OFFY : 0;
                float fm = bm ? 1.f : 0.f, fp2 = bp ? 1.f : 0.f;
                f32x4 v0 = *(const f32x4*)&Tb[base];
                f32x4 vm = *(const f32x4*)&Tb[base - offm];
                f32x4 vp = *(const f32x4*)&Tb[base + offp];
                f32x4 rv = *(const f32x4*)&rn[qq0];
                s = (v0 + fm*vm + fp2*vp) * rv;
            }
            *(f32x4*)&Sl[r][j*4] = s;
        }
    } else {
        for (int idx = t; idx < 10*264; idx += 256) {
            int r = idx / 264, c = idx - r*264;
            int pp = p0 - 1 + r, qq = q0 - 4 + c;
            float s = 0.f;
            if ((unsigned)pp < KL && (unsigned)qq < KL) {
                size_t base = (size_t)pp*KL + qq;
                float acc = Tb[base];
                if (pp >= KHS && qq >= KHS)         acc += Tb[base - OFFY];
                if (pp < KL - KHS && qq < KL - KHS) acc += Tb[base + OFFY];
                s = acc * rn[qq];
            }
            Sl[r][c] = s;
        }
    }
    __syncthreads();
    float w[9];
    #pragma unroll
    for (int i = 0; i < 9; i++) w[i] = fw[i];
    int q = q0 + t;
    float h0[10], h1[10], h2[10];
    #pragma unroll
    for (int r = 0; r < 10; r++) {
        float s0 = Sl[r][t+3], s1 = Sl[r][t+4], s2 = Sl[r][t+5];
        h0[r] = w[0]*s0 + w[1]*s1 + w[2]*s2;
        h1[r] = w[3]*s0 + w[4]*s1 + w[5]*s2;
        h2[r] = w[6]*s0 + w[7]*s1 + w[8]*s2;
    }
    #pragma unroll
    for (int rr = 0; rr < 8; rr++) {
        Y1[((size_t)bi*KL + p0 + rr)*KL + q] = h0[rr] + h1[rr+1] + h2[rr+2];
    }
}

// ------ K5 v4: fuse conv #2 (transposed flat) + softmax -> bf16 -------------
// Closed-form tap addresses: center gather == q; taps are q-/+48 except at
// the v=0 / v=47 seams (qm = 2255+q for q<48; qp = q-2255 for q>2255);
// validity q!=0 / q!=2303. Zero div/mod in the hot loop.
__global__ __launch_bounds__(256) void k_fuse_b(const float* __restrict__ Y1,
    const float* __restrict__ fw, const float* __restrict__ mm,
    unsigned short* __restrict__ Ybf)
{
    __shared__ float rowb[4][KL];   // 36864 B
    __shared__ float red[8];
    int blk = blockIdx.x;           // nb*1152
    int tp0 = (blk % 1152)*2;
    int bi  = blk / 1152;
    int t = threadIdx.x;
    const float* Yb = Y1 + (size_t)bi*KL*KL;
    #pragma unroll
    for (int a = 0; a < 4; a++) {
        int t2 = tp0 - 1 + a;
        float4* dst = (float4*)&rowb[a][0];
        if ((unsigned)t2 < KL) {
            int pr = (t2 % KHS)*KHS + t2/KHS;
            const float4* src = (const float4*)&Yb[(size_t)pr*KL];
            for (int i = t; i < KL/4; i += 256) dst[i] = src[i];
        } else {
            float4 z = {0.f,0.f,0.f,0.f};
            for (int i = t; i < KL/4; i += 256) dst[i] = z;
        }
    }
    float w9[9];
    #pragma unroll
    for (int i = 0; i < 9; i++) w9[i] = fw[i];
    __syncthreads();
    int w = t >> 6, lane = t & 63;
    int half = w >> 1;
    int l128 = t & 127;
    int tp = tp0 + half;
    int x = tp / KHS, y = tp - x*KHS;   // tp = x*48 + y
    int p = y*KHS + x;
    const float* mmb = mm + bi*KL;
    float vals[18];
    float lmax = -1e30f;
    #pragma unroll
    for (int i = 0; i < 18; i++) {
        int q = l128 + i*128;
        int qm = (q >= KHS)      ? q - KHS : 2255 + q;
        int qp = (q <= KL-1-KHS) ? q + KHS : q - 2255;
        float fm = (q != 0)    ? 1.f : 0.f;
        float fp = (q != KL-1) ? 1.f : 0.f;
        float am = w9[0]*rowb[half][qm] + w9[3]*rowb[half+1][qm] + w9[6]*rowb[half+2][qm];
        float a0 = w9[1]*rowb[half][q]  + w9[4]*rowb[half+1][q]  + w9[7]*rowb[half+2][q];
        float ap = w9[2]*rowb[half][qp] + w9[5]*rowb[half+1][qp] + w9[8]*rowb[half+2][qp];
        float val = (fm*am + a0 + fp*ap) * mmb[q] * 10.0f;
        vals[i] = val;
        lmax = fmaxf(lmax, val);
    }
    #pragma unroll
    for (int off = 32; off > 0; off >>= 1) lmax = fmaxf(lmax, __shfl_down(lmax, off));
    if (lane == 0) red[w] = lmax;
    __syncthreads();
    lmax = fmaxf(red[half*2], red[half*2 + 1]);
    float lsum = 0.f;
    #pragma unroll
    for (int i = 0; i < 18; i++) {
        float e = __expf(vals[i] - lmax);
        vals[i] = e;
        lsum += e;
    }
    #pragma unroll
    for (int off = 32; off > 0; off >>= 1) lsum += __shfl_down(lsum, off);
    if (lane == 0) red[4 + w] = lsum;
    __syncthreads();
    lsum = red[4 + half*2] + red[4 + half*2 + 1];
    float inv = 1.0f / lsum;
    unsigned short* orow = Ybf + ((size_t)bi*KL + p)*KL;
    #pragma unroll
    for (int i = 0; i < 18; i++) {
        int q = l128 + i*128;
        orow[q] = f2bf(vals[i]*inv*mmb[q]);
    }
}

// ---------------- KR: Rt[n][k] bf16, n=(ky,kx,c), k=q -----------------------
__global__ __launch_bounds__(256) void k_buildRt(const float* __restrict__ bsrc,
    unsigned short* __restrict__ Rt)
{
    int idx = blockIdx.x*256 + threadIdx.x;   // nb*1024*288
    int k8 = idx % 288;
    int rest = idx / 288;
    int n  = rest % 1024;
    int bi = rest / 1024;
    int jj = n >> 6, c = n & 63;
    int ky = jj >> 2, kx = jj & 3;
    int k0 = k8*8;
    bf16x8 vv;
    #pragma unroll
    for (int j = 0; j < 8; j++) {
        int q = k0 + j;
        int v = q / KHS, u = q % KHS;
        int ry = 2*v + ky - 1, rx = 2*u + kx - 1;
        float val = 0.f;
        if ((unsigned)ry < KHH && (unsigned)rx < KHH)
            val = bsrc[(((size_t)bi*KHH + ry)*KHH + rx)*KC + c];
        vv[j] = (short)f2bf(val);
    }
    *(bf16x8*)&Rt[((size_t)bi*1024 + n)*KL + k0] = vv;
}

// -------- K8: overlap-add over 3 bf16 split-K partials, 4 channels/thread ---
__global__ __launch_bounds__(256) void k_overlap(const unsigned short* __restrict__ P,
    float* __restrict__ out, size_t psize)
{
    size_t gid = (size_t)blockIdx.x*256 + threadIdx.x;   // nb*96*96*16
    int c4 = (int)(gid & 15)*4;
    size_t r = gid >> 4;
    int ix = (int)(r % KHH); r /= KHH;
    int iy = (int)(r % KHH);
    int bi = (int)(r / KHH);
    f32x4 acc = (f32x4){0.f,0.f,0.f,0.f};
    #pragma unroll
    for (int sy = 0; sy < 2; sy++) {
        int ky = (iy & 1) ? (sy*2) : (sy*2 + 1);
        int yp = (iy + 1 - ky) >> 1;
        if ((unsigned)yp >= KHS) continue;
        #pragma unroll
        for (int sx = 0; sx < 2; sx++) {
            int kx = (ix & 1) ? (sx*2) : (sx*2 + 1);
            int xp = (ix + 1 - kx) >> 1;
            if ((unsigned)xp >= KHS) continue;
            size_t idx = (((size_t)bi*KL + yp*KHS + xp)*16 + (ky*4 + kx))*64 + c4;
            #pragma unroll
            for (int s = 0; s < 3; s++) {
                bf16x4 v = *(const bf16x4*)&P[idx + s*psize];
                #pragma unroll
                for (int j = 0; j < 4; j++)
                    acc[j] += bf2f((unsigned short)v[j]);
            }
        }
    }
    f32x4 o = acc * 0.25f;
    *(f32x4*)&out[(((size_t)bi*KHH + iy)*KHH + ix)*KC + c4] = o;
}

extern "C" void kernel_launch(void* const* d_in, const int* in_sizes, int n_in,
                              void* d_out, int out_size, void* d_ws, size_t ws_size,
                              hipStream_t stream)
{
    const float* f    = (const float*)d_in[0];
    const float* b    = (const float*)d_in[1];
    const float* mask = (const float*)d_in[2];
    const float* fw   = (const float*)d_in[3];
    float* out = (float*)d_out;

    auto need = [](int nbc) -> size_t {
        return (size_t)nbc * (2ull*KL*KC + 4ull*KL + 2ull*(size_t)KL*KL) * 4ull;
    };
    int nbc = 4;
    if (need(nbc) > ws_size) nbc = 2;
    if (need(nbc) > ws_size) nbc = 1;

    for (int bi0 = 0; bi0 < 4; bi0 += nbc) {
        int nb = (4 - bi0 < nbc) ? (4 - bi0) : nbc;
        const float* fc = f    + (size_t)bi0*KHH*KHH*KC;
        const float* bc = b    + (size_t)bi0*KHH*KHH*KC;
        const float* mc = mask + (size_t)bi0*KHH*KHH;
        float* outc = out + (size_t)bi0*KHH*KHH*KC;

        float* w    = (float*)d_ws;
        float* nbuf = w;  w += (size_t)nbc*KL;
        float* mdd  = w;  w += (size_t)nbc*KL;
        float* rnrm = w;  w += (size_t)nbc*KL;
        float* mmb  = w;  w += (size_t)nbc*KL;
        float* bufA = w;  w += (size_t)nbc*KL*KL;
        float* bufB = w;
        // lifetimes:
        //  bufB: [Ahat|Bhat] (bf16) -> Y1 (fp32) -> P0..P2 (bf16)
        //  bufA: T (fp32) -> [Ybf bf16 | Rt bf16]
        unsigned short* Ahat = (unsigned short*)bufB;
        unsigned short* Bhat = Ahat + (size_t)nbc*KL*576;
        float* Tbuf = bufA;
        float* Y1   = bufB;
        unsigned short* Ybf = (unsigned short*)bufA;
        unsigned short* Rtb = Ybf + (size_t)nbc*KL*KL;
        unsigned short* Pbuf = (unsigned short*)bufB;
        size_t psize = (size_t)nbc*KL*1024;   // one split-K partial (elements)

        k_prep2     <<<nb*KL, 64, 0, stream>>>(fc, bc, mc, nbuf, mdd, Ahat, Bhat);
        k_normmask  <<<(nb*KL)/256, 256, 0, stream>>>(nbuf, mdd, rnrm, mmb);
        // T = Ahat * Bhat^T  (K=576, no split, fp32 out)
        k_mfma_bt<18,false><<<dim3(18, 18, nb), 256, 0, stream>>>(
            Ahat, Bhat, Tbuf, KL, (size_t)KL*576, (size_t)KL*576, (size_t)KL*KL,
            576, 1, 0);
        // y-diag 3-tap * rnrm + fuse1: T (bufA) -> Y1 (bufB)
        k_fuse_a2   <<<dim3(9, 288, nb), 256, 0, stream>>>(Tbuf, rnrm, fw, Y1);
        // fuse2 + softmax: Y1 (bufB) -> Ybf (bufA)
        k_fuse_b    <<<nb*1152, 256, 0, stream>>>(Y1, fw, mmb, Ybf);
        k_buildRt   <<<(nb*1024*288)/256, 256, 0, stream>>>(bc, Rtb);
        // P = Ybf * Rt^T (K=2304, split-K=3, bf16 partials P0..P2)
        k_mfma_bt<24,true><<<dim3(8, 18, nb*3), 256, 0, stream>>>(
            Ybf, Rtb, Pbuf, 1024, (size_t)KL*KL, (size_t)1024*KL, (size_t)KL*1024,
            2304, 3, psize);
        k_overlap   <<<nb*KL/4*16/16, 256, 0, stream>>>(Pbuf, outc, psize);
    }
}

// Round 11
// 319.662 us; speedup vs baseline: 1.5009x; 1.0625x over previous
//
#include <hip/hip_runtime.h>
#include <hip/hip_bf16.h>

#define KL  2304   // 48*48
#define KC  64
#define KHS 48
#define KHH 96
#define OFFY (KHS*(KL + 1))    // flat offset for (p+48,q+48)

typedef __attribute__((ext_vector_type(8))) short bf16x8;
typedef __attribute__((ext_vector_type(4))) short bf16x4;
typedef __attribute__((ext_vector_type(8))) _Float16 f16x8;
typedef __attribute__((ext_vector_type(4))) float f32x4;

static __device__ inline unsigned short f2bf(float x) {
    __hip_bfloat16 h = __float2bfloat16(x);
    return *reinterpret_cast<unsigned short*>(&h);
}
static __device__ inline float bf2f(unsigned short u) {
    unsigned v = ((unsigned)u) << 16;
    return __uint_as_float(v);
}
static __device__ inline unsigned short f2h(float x) {
    _Float16 h = (_Float16)x;
    return *reinterpret_cast<unsigned short*>(&h);
}

// ---- K0': downsample + |bd|^2 + mask + fp16 x-shift operands (K=192) -------
// k = dxi*64 + c. Zeroed when px+dxi-1 leaves [0,48).
__global__ __launch_bounds__(64) void k_prep2(const float* __restrict__ f,
    const float* __restrict__ bsrc, const float* __restrict__ mask,
    float* __restrict__ nbuf, float* __restrict__ mdd,
    unsigned short* __restrict__ Ahat, unsigned short* __restrict__ Bhat)
{
    int blk = blockIdx.x;              // nb*KL blocks
    int p = blk % KL, bi = blk / KL;
    int y = p / KHS, x = p % KHS;
    int fy = 2*y + 1;
    int c = threadIdx.x;
    unsigned short* Ap = Ahat + ((size_t)bi*KL + p)*192;
    unsigned short* Bp = Bhat + ((size_t)bi*KL + p)*192;
    float bc = 0.f;
    #pragma unroll
    for (int dxi = 0; dxi < 3; dxi++) {
        int xx = x + dxi - 1;
        float av = 0.f, bv = 0.f;
        if ((unsigned)xx < KHS) {
            int fxx = 2*xx + 1;
            size_t src = (((size_t)bi*KHH + fy)*KHH + fxx)*KC + c;
            av = f[src]; bv = bsrc[src];
        }
        if (dxi == 1) bc = bv;
        Ap[dxi*64 + c] = f2h(av);
        Bp[dxi*64 + c] = f2h(bv);
    }
    float s = bc*bc;
    #pragma unroll
    for (int off = 32; off > 0; off >>= 1) s += __shfl_down(s, off);
    if (c == 0) {
        nbuf[bi*KL + p] = s;
        mdd[bi*KL + p]  = mask[((size_t)bi*KHH + fy)*KHH + (2*x + 1)];
    }
}

// ------- K1: rnrm[q] = 1/max(sqrt(9-tap sum nb),1e-4); mm from mask --------
__global__ __launch_bounds__(256) void k_normmask(const float* __restrict__ nbuf,
    const float* __restrict__ mdd, float* __restrict__ rnrm, float* __restrict__ mm)
{
    int i = blockIdx.x*256 + threadIdx.x;   // nb*KL
    int q = i % KL, bi = i / KL;
    int v = q / KHS, u = q % KHS;
    float sn = 0.f, sm = 0.f;
    for (int dy = -1; dy <= 1; dy++) {
        int vv = v + dy; if ((unsigned)vv >= KHS) continue;
        for (int dx = -1; dx <= 1; dx++) {
            int uu = u + dx; if ((unsigned)uu >= KHS) continue;
            sn += nbuf[bi*KL + vv*KHS + uu];
            sm += mdd[bi*KL + vv*KHS + uu];
        }
    }
    rnrm[i] = 1.0f / fmaxf(sqrtf(sn), 1e-4f);
    mm[i]   = (sm == 0.0f) ? 1.0f : 0.0f;
}

// ------ MFMA GEMM: C = A * B^T, split-K, fp32/bf16 out, fp16/bf16 in, XCD swz
template<int KITERS, bool OUTBF16, bool INFP16>
__global__ __launch_bounds__(256) void k_mfma_bt(const unsigned short* __restrict__ A,
    const unsigned short* __restrict__ B, void* __restrict__ Cv,
    int Ncols, size_t sA, size_t sB, size_t sC, int KDIM, int nsplit, size_t psize)
{
    int flat = blockIdx.x + gridDim.x*(blockIdx.y + gridDim.y*blockIdx.z);
    int nxy = gridDim.x*gridDim.y;
    int per = (nxy*gridDim.z) >> 3;
    int g = (flat & 7)*per + (flat >> 3);
    int z = g / nxy; int r = g - z*nxy;
    int by = r / gridDim.x; int bx = r - by*gridDim.x;

    int ks = z % nsplit, bi = z / nsplit;
    int kbase = ks * KITERS * 32;
    int n0 = bx*128, m0 = by*128;
    const unsigned short* Ab = A + (size_t)bi*sA;
    const unsigned short* Bb = B + (size_t)bi*sB;
    __shared__ unsigned short As[128*32];
    __shared__ unsigned short Bs[128*32];
    int t = threadIdx.x;
    int lane = t & 63, w = t >> 6;
    int l15 = lane & 15, quad = lane >> 4;
    int swf = (l15 >> 2) & 3;
    int wm = (w >> 1)*64, wn = (w & 1)*64;
    int srow = lane >> 2;
    int ch = lane & 3;
    f32x4 acc[4][4];
    #pragma unroll
    for (int i = 0; i < 4; i++)
        #pragma unroll
        for (int j = 0; j < 4; j++) acc[i][j] = (f32x4){0.f,0.f,0.f,0.f};

    for (int kk = 0; kk < KITERS; kk++) {
        int k0 = kbase + kk*32;
        #pragma unroll
        for (int i = 0; i < 2; i++) {
            int rbase = w*32 + i*16;
            int r2 = rbase + srow;
            int cs = (ch ^ ((r2 >> 2) & 3))*8;
            const unsigned short* ga = &Ab[(size_t)(m0 + r2)*KDIM + k0 + cs];
            __builtin_amdgcn_global_load_lds(
                (const __attribute__((address_space(1))) void*)ga,
                (__attribute__((address_space(3))) void*)&As[rbase*32], 16, 0, 0);
            const unsigned short* gb = &Bb[(size_t)(n0 + r2)*KDIM + k0 + cs];
            __builtin_amdgcn_global_load_lds(
                (const __attribute__((address_space(1))) void*)gb,
                (__attribute__((address_space(3))) void*)&Bs[rbase*32], 16, 0, 0);
        }
        __syncthreads();
        if (INFP16) {
            f16x8 af[4], bfr[4];
            #pragma unroll
            for (int mi = 0; mi < 4; mi++)
                af[mi] = *(const f16x8*)&As[(wm + mi*16 + l15)*32 + ((quad ^ swf)*8)];
            #pragma unroll
            for (int ni = 0; ni < 4; ni++)
                bfr[ni] = *(const f16x8*)&Bs[(wn + ni*16 + l15)*32 + ((quad ^ swf)*8)];
            #pragma unroll
            for (int mi = 0; mi < 4; mi++)
                #pragma unroll
                for (int ni = 0; ni < 4; ni++)
                    acc[mi][ni] = __builtin_amdgcn_mfma_f32_16x16x32_f16(
                        af[mi], bfr[ni], acc[mi][ni], 0, 0, 0);
        } else {
            bf16x8 af[4], bfr[4];
            #pragma unroll
            for (int mi = 0; mi < 4; mi++)
                af[mi] = *(const bf16x8*)&As[(wm + mi*16 + l15)*32 + ((quad ^ swf)*8)];
            #pragma unroll
            for (int ni = 0; ni < 4; ni++)
                bfr[ni] = *(const bf16x8*)&Bs[(wn + ni*16 + l15)*32 + ((quad ^ swf)*8)];
            #pragma unroll
            for (int mi = 0; mi < 4; mi++)
                #pragma unroll
                for (int ni = 0; ni < 4; ni++)
                    acc[mi][ni] = __builtin_amdgcn_mfma_f32_16x16x32_bf16(
                        af[mi], bfr[ni], acc[mi][ni], 0, 0, 0);
        }
        __syncthreads();
    }
    if (OUTBF16) {
        unsigned short* Cb = (unsigned short*)Cv + (size_t)ks*psize + (size_t)bi*sC;
        #pragma unroll
        for (int mi = 0; mi < 4; mi++)
            #pragma unroll
            for (int ni = 0; ni < 4; ni++) {
                int col = n0 + wn + ni*16 + l15;
                #pragma unroll
                for (int r2 = 0; r2 < 4; r2++) {
                    int row = m0 + wm + mi*16 + quad*4 + r2;
                    Cb[(size_t)row*Ncols + col] = f2bf(acc[mi][ni][r2]);
                }
            }
    } else {
        float* Cb = (float*)Cv + (size_t)ks*psize + (size_t)bi*sC;
        #pragma unroll
        for (int mi = 0; mi < 4; mi++)
            #pragma unroll
            for (int ni = 0; ni < 4; ni++) {
                int col = n0 + wn + ni*16 + l15;
                #pragma unroll
                for (int r2 = 0; r2 < 4; r2++) {
                    int row = m0 + wm + mi*16 + quad*4 + r2;
                    Cb[(size_t)row*Ncols + col] = acc[mi][ni][r2];
                }
            }
    }
}

// ------ K3b v2: y-diagonal 3-tap * rnrm + fuse conv #1 ----------------------
__global__ __launch_bounds__(256) void k_fuse_a2(const float* __restrict__ T,
    const float* __restrict__ rnrm, const float* __restrict__ fw,
    float* __restrict__ Y1)
{
    __shared__ float Sl[10][272];
    int bi = blockIdx.z;
    int qt = blockIdx.x;
    int p0 = blockIdx.y*8, q0 = qt*256;
    const float* Tb = T + (size_t)bi*KL*KL;
    const float* rn = rnrm + bi*KL;
    int t = threadIdx.x;
    bool edge = (qt == 0) | (qt == 8);
    if (!edge) {
        for (int idx = t; idx < 10*66; idx += 256) {
            int r = idx / 66, j = idx - r*66;
            int pp = p0 - 1 + r;
            int qq0 = q0 - 4 + j*4;
            f32x4 s = (f32x4){0.f,0.f,0.f,0.f};
            if ((unsigned)pp < KL) {
                size_t base = (size_t)pp*KL + qq0;
                bool bm = (pp >= KHS), bp = (pp < KL - KHS);
                size_t offm = bm ? (size_t)OFFY : 0;
                size_t offp = bp ? (size_t)OFFY : 0;
                float fm = bm ? 1.f : 0.f, fp2 = bp ? 1.f : 0.f;
                f32x4 v0 = *(const f32x4*)&Tb[base];
                f32x4 vm = *(const f32x4*)&Tb[base - offm];
                f32x4 vp = *(const f32x4*)&Tb[base + offp];
                f32x4 rv = *(const f32x4*)&rn[qq0];
                s = (v0 + fm*vm + fp2*vp) * rv;
            }
            *(f32x4*)&Sl[r][j*4] = s;
        }
    } else {
        for (int idx = t; idx < 10*264; idx += 256) {
            int r = idx / 264, c = idx - r*264;
            int pp = p0 - 1 + r, qq = q0 - 4 + c;
            float s = 0.f;
            if ((unsigned)pp < KL && (unsigned)qq < KL) {
                size_t base = (size_t)pp*KL + qq;
                float acc = Tb[base];
                if (pp >= KHS && qq >= KHS)         acc += Tb[base - OFFY];
                if (pp < KL - KHS && qq < KL - KHS) acc += Tb[base + OFFY];
                s = acc * rn[qq];
            }
            Sl[r][c] = s;
        }
    }
    __syncthreads();
    float w[9];
    #pragma unroll
    for (int i = 0; i < 9; i++) w[i] = fw[i];
    int q = q0 + t;
    float h0[10], h1[10], h2[10];
    #pragma unroll
    for (int r = 0; r < 10; r++) {
        float s0 = Sl[r][t+3], s1 = Sl[r][t+4], s2 = Sl[r][t+5];
        h0[r] = w[0]*s0 + w[1]*s1 + w[2]*s2;
        h1[r] = w[3]*s0 + w[4]*s1 + w[5]*s2;
        h2[r] = w[6]*s0 + w[7]*s1 + w[8]*s2;
    }
    #pragma unroll
    for (int rr = 0; rr < 8; rr++) {
        Y1[((size_t)bi*KL + p0 + rr)*KL + q] = h0[rr] + h1[rr+1] + h2[rr+2];
    }
}

// ------ K5 v4: fuse conv #2 (transposed flat) + softmax -> bf16 -------------
__global__ __launch_bounds__(256) void k_fuse_b(const float* __restrict__ Y1,
    const float* __restrict__ fw, const float* __restrict__ mm,
    unsigned short* __restrict__ Ybf)
{
    __shared__ float rowb[4][KL];   // 36864 B
    __shared__ float red[8];
    int blk = blockIdx.x;           // nb*1152
    int tp0 = (blk % 1152)*2;
    int bi  = blk / 1152;
    int t = threadIdx.x;
    const float* Yb = Y1 + (size_t)bi*KL*KL;
    #pragma unroll
    for (int a = 0; a < 4; a++) {
        int t2 = tp0 - 1 + a;
        float4* dst = (float4*)&rowb[a][0];
        if ((unsigned)t2 < KL) {
            int pr = (t2 % KHS)*KHS + t2/KHS;
            const float4* src = (const float4*)&Yb[(size_t)pr*KL];
            for (int i = t; i < KL/4; i += 256) dst[i] = src[i];
        } else {
            float4 z = {0.f,0.f,0.f,0.f};
            for (int i = t; i < KL/4; i += 256) dst[i] = z;
        }
    }
    float w9[9];
    #pragma unroll
    for (int i = 0; i < 9; i++) w9[i] = fw[i];
    __syncthreads();
    int w = t >> 6, lane = t & 63;
    int half = w >> 1;
    int l128 = t & 127;
    int tp = tp0 + half;
    int x = tp / KHS, y = tp - x*KHS;   // tp = x*48 + y
    int p = y*KHS + x;
    const float* mmb = mm + bi*KL;
    float vals[18];
    float lmax = -1e30f;
    #pragma unroll
    for (int i = 0; i < 18; i++) {
        int q = l128 + i*128;
        int qm = (q >= KHS)      ? q - KHS : 2255 + q;
        int qp = (q <= KL-1-KHS) ? q + KHS : q - 2255;
        float fm = (q != 0)    ? 1.f : 0.f;
        float fp = (q != KL-1) ? 1.f : 0.f;
        float am = w9[0]*rowb[half][qm] + w9[3]*rowb[half+1][qm] + w9[6]*rowb[half+2][qm];
        float a0 = w9[1]*rowb[half][q]  + w9[4]*rowb[half+1][q]  + w9[7]*rowb[half+2][q];
        float ap = w9[2]*rowb[half][qp] + w9[5]*rowb[half+1][qp] + w9[8]*rowb[half+2][qp];
        float val = (fm*am + a0 + fp*ap) * mmb[q] * 10.0f;
        vals[i] = val;
        lmax = fmaxf(lmax, val);
    }
    #pragma unroll
    for (int off = 32; off > 0; off >>= 1) lmax = fmaxf(lmax, __shfl_down(lmax, off));
    if (lane == 0) red[w] = lmax;
    __syncthreads();
    lmax = fmaxf(red[half*2], red[half*2 + 1]);
    float lsum = 0.f;
    #pragma unroll
    for (int i = 0; i < 18; i++) {
        float e = __expf(vals[i] - lmax);
        vals[i] = e;
        lsum += e;
    }
    #pragma unroll
    for (int off = 32; off > 0; off >>= 1) lsum += __shfl_down(lsum, off);
    if (lane == 0) red[4 + w] = lsum;
    __syncthreads();
    lsum = red[4 + half*2] + red[4 + half*2 + 1];
    float inv = 1.0f / lsum;
    unsigned short* orow = Ybf + ((size_t)bi*KL + p)*KL;
    #pragma unroll
    for (int i = 0; i < 18; i++) {
        int q = l128 + i*128;
        orow[q] = f2bf(vals[i]*inv*mmb[q]);
    }
}

// ---------------- KR: Rt[n][k] bf16, n=(ky,kx,c), k=q -----------------------
__global__ __launch_bounds__(256) void k_buildRt(const float* __restrict__ bsrc,
    unsigned short* __restrict__ Rt)
{
    int idx = blockIdx.x*256 + threadIdx.x;   // nb*1024*288
    int k8 = idx % 288;
    int rest = idx / 288;
    int n  = rest % 1024;
    int bi = rest / 1024;
    int jj = n >> 6, c = n & 63;
    int ky = jj >> 2, kx = jj & 3;
    int k0 = k8*8;
    bf16x8 vv;
    #pragma unroll
    for (int j = 0; j < 8; j++) {
        int q = k0 + j;
        int v = q / KHS, u = q % KHS;
        int ry = 2*v + ky - 1, rx = 2*u + kx - 1;
        float val = 0.f;
        if ((unsigned)ry < KHH && (unsigned)rx < KHH)
            val = bsrc[(((size_t)bi*KHH + ry)*KHH + rx)*KC + c];
        vv[j] = (short)f2bf(val);
    }
    *(bf16x8*)&Rt[((size_t)bi*1024 + n)*KL + k0] = vv;
}

// -------- K8: overlap-add over 3 bf16 split-K partials, 4 channels/thread ---
__global__ __launch_bounds__(256) void k_overlap(const unsigned short* __restrict__ P,
    float* __restrict__ out, size_t psize)
{
    size_t gid = (size_t)blockIdx.x*256 + threadIdx.x;   // nb*96*96*16
    int c4 = (int)(gid & 15)*4;
    size_t r = gid >> 4;
    int ix = (int)(r % KHH); r /= KHH;
    int iy = (int)(r % KHH);
    int bi = (int)(r / KHH);
    f32x4 acc = (f32x4){0.f,0.f,0.f,0.f};
    #pragma unroll
    for (int sy = 0; sy < 2; sy++) {
        int ky = (iy & 1) ? (sy*2) : (sy*2 + 1);
        int yp = (iy + 1 - ky) >> 1;
        if ((unsigned)yp >= KHS) continue;
        #pragma unroll
        for (int sx = 0; sx < 2; sx++) {
            int kx = (ix & 1) ? (sx*2) : (sx*2 + 1);
            int xp = (ix + 1 - kx) >> 1;
            if ((unsigned)xp >= KHS) continue;
            size_t idx = (((size_t)bi*KL + yp*KHS + xp)*16 + (ky*4 + kx))*64 + c4;
            #pragma unroll
            for (int s = 0; s < 3; s++) {
                bf16x4 v = *(const bf16x4*)&P[idx + s*psize];
                #pragma unroll
                for (int j = 0; j < 4; j++)
                    acc[j] += bf2f((unsigned short)v[j]);
            }
        }
    }
    f32x4 o = acc * 0.25f;
    *(f32x4*)&out[(((size_t)bi*KHH + iy)*KHH + ix)*KC + c4] = o;
}

extern "C" void kernel_launch(void* const* d_in, const int* in_sizes, int n_in,
                              void* d_out, int out_size, void* d_ws, size_t ws_size,
                              hipStream_t stream)
{
    const float* f    = (const float*)d_in[0];
    const float* b    = (const float*)d_in[1];
    const float* mask = (const float*)d_in[2];
    const float* fw   = (const float*)d_in[3];
    float* out = (float*)d_out;

    auto need = [](int nbc) -> size_t {
        return (size_t)nbc * (2ull*KL*KC + 4ull*KL + 2ull*(size_t)KL*KL) * 4ull;
    };
    int nbc = 4;
    if (need(nbc) > ws_size) nbc = 2;
    if (need(nbc) > ws_size) nbc = 1;

    for (int bi0 = 0; bi0 < 4; bi0 += nbc) {
        int nb = (4 - bi0 < nbc) ? (4 - bi0) : nbc;
        const float* fc = f    + (size_t)bi0*KHH*KHH*KC;
        const float* bc = b    + (size_t)bi0*KHH*KHH*KC;
        const float* mc = mask + (size_t)bi0*KHH*KHH;
        float* outc = out + (size_t)bi0*KHH*KHH*KC;

        float* w    = (float*)d_ws;
        float* nbuf = w;  w += (size_t)nbc*KL;
        float* mdd  = w;  w += (size_t)nbc*KL;
        float* rnrm = w;  w += (size_t)nbc*KL;
        float* mmb  = w;  w += (size_t)nbc*KL;
        float* bufA = w;  w += (size_t)nbc*KL*KL;
        float* bufB = w;
        // lifetimes:
        //  bufB: [Ahat|Bhat] (fp16, 7.1 MB ea) -> Y1 (fp32) -> P0..P2 (bf16)
        //  bufA: T (fp32) -> [Ybf bf16 | Rt bf16]
        unsigned short* Ahat = (unsigned short*)bufB;
        unsigned short* Bhat = Ahat + (size_t)nbc*KL*192;
        float* Tbuf = bufA;
        float* Y1   = bufB;
        unsigned short* Ybf = (unsigned short*)bufA;
        unsigned short* Rtb = Ybf + (size_t)nbc*KL*KL;
        unsigned short* Pbuf = (unsigned short*)bufB;
        size_t psize = (size_t)nbc*KL*1024;   // one split-K partial (elements)

        k_prep2     <<<nb*KL, 64, 0, stream>>>(fc, bc, mc, nbuf, mdd, Ahat, Bhat);
        k_normmask  <<<(nb*KL)/256, 256, 0, stream>>>(nbuf, mdd, rnrm, mmb);
        // T = Ahat * Bhat^T  (K=192 fp16 single-segment, fp32 out)
        k_mfma_bt<6,false,true><<<dim3(18, 18, nb), 256, 0, stream>>>(
            Ahat, Bhat, Tbuf, KL, (size_t)KL*192, (size_t)KL*192, (size_t)KL*KL,
            192, 1, 0);
        // y-diag 3-tap * rnrm + fuse1: T (bufA) -> Y1 (bufB)
        k_fuse_a2   <<<dim3(9, 288, nb), 256, 0, stream>>>(Tbuf, rnrm, fw, Y1);
        // fuse2 + softmax: Y1 (bufB) -> Ybf (bufA)
        k_fuse_b    <<<nb*1152, 256, 0, stream>>>(Y1, fw, mmb, Ybf);
        k_buildRt   <<<(nb*1024*288)/256, 256, 0, stream>>>(bc, Rtb);
        // P = Ybf * Rt^T (K=2304 bf16, split-K=3, bf16 partials P0..P2)
        k_mfma_bt<24,true,false><<<dim3(8, 18, nb*3), 256, 0, stream>>>(
            Ybf, Rtb, Pbuf, 1024, (size_t)KL*KL, (size_t)1024*KL, (size_t)KL*1024,
            2304, 3, psize);
        k_overlap   <<<nb*KL/4*16/16, 256, 0, stream>>>(Pbuf, outc, psize);
    }
}